// Round 12
// baseline (541.733 us; speedup 1.0000x reference)
//
#include <hip/hip_runtime.h>
#include <hip/hip_bf16.h>

#define B_ 8
#define T_ 2048
#define C_ 1024
#define S_ 1024      // top_k == reduced sequence length
#define H_ 16
#define DH_ 64
#define DFF_ 4096
#define M_ (B_*S_)   // 8192 rows through the block

typedef __attribute__((ext_vector_type(8))) short bf16x8;
typedef __attribute__((ext_vector_type(4))) float f32x4;

__device__ __forceinline__ short f2bf(float f) {
  __hip_bfloat16 h = __float2bfloat16(f);
  return *reinterpret_cast<short*>(&h);
}
__device__ __forceinline__ float bf2f(short s) {
  __hip_bfloat16 h = *reinterpret_cast<__hip_bfloat16*>(&s);
  return __bfloat162float(h);
}

typedef const __attribute__((address_space(1))) unsigned int* gas_p;
typedef __attribute__((address_space(3))) unsigned int* las_p;
__device__ __forceinline__ void gload_lds16(const void* g, void* l) {
  __builtin_amdgcn_global_load_lds((gas_p)g, (las_p)l, 16, 0, 0);
}

// ---------------- router logits: one wave per token ----------------
__global__ __launch_bounds__(256) void k_router(const float* __restrict__ x,
    const float* __restrict__ wr, float* __restrict__ logits) {
  int tok = blockIdx.x * 4 + (threadIdx.x >> 6);
  int l = threadIdx.x & 63;
  const float* xr = x + (size_t)tok * C_;
  float s = 0.f;
  #pragma unroll
  for (int j = 0; j < C_/64; ++j) s += xr[l + 64*j] * wr[l + 64*j];
  #pragma unroll
  for (int m = 32; m; m >>= 1) s += __shfl_xor(s, m);
  if (l == 0) logits[tok] = s;
}

// -------- init inverse map to -1 --------
__global__ __launch_bounds__(256) void k_initmap(int* __restrict__ map) {
  int i = blockIdx.x*256 + threadIdx.x;
  ((int4*)map)[i] = make_int4(-1, -1, -1, -1);
}

// ------------- exact top-k via bitonic sort (1 block / batch) -------------
// also writes inverse map: map[b*T + token] = k
__global__ __launch_bounds__(1024) void k_topk(const float* __restrict__ logits,
    int* __restrict__ idx, float* __restrict__ wts, int* __restrict__ map) {
  __shared__ unsigned long long key[2048];
  int b = blockIdx.x, t = threadIdx.x;
  for (int i = t; i < T_; i += 1024) {
    float v = logits[(size_t)b*T_ + i];
    unsigned u = __float_as_uint(v);
    unsigned so = u ^ ((u >> 31) ? 0xFFFFFFFFu : 0x80000000u);
    key[i] = ((unsigned long long)(~so) << 32) | (unsigned)i;
  }
  __syncthreads();
  for (int k = 2; k <= 2048; k <<= 1) {
    for (int j = k >> 1; j > 0; j >>= 1) {
      int i = ((t & ~(j-1)) << 1) | (t & (j-1));
      int ix = i | j;
      unsigned long long a = key[i], c = key[ix];
      bool up = ((i & k) == 0);
      if ((a > c) == up) { key[i] = c; key[ix] = a; }
      __syncthreads();
    }
  }
  unsigned long long a = key[t];
  __syncthreads();
  unsigned i0 = (unsigned)(a & 0xFFFFFFFFu);
  unsigned so = ~(unsigned)(a >> 32);
  unsigned bits = (so & 0x80000000u) ? (so ^ 0x80000000u) : ~so;
  key[t] = ((unsigned long long)i0 << 32) | bits;
  __syncthreads();
  for (int k = 2; k <= 1024; k <<= 1) {
    for (int j = k >> 1; j > 0; j >>= 1) {
      if (t < 512) {
        int i = ((t & ~(j-1)) << 1) | (t & (j-1));
        int ix = i | j;
        unsigned long long a2 = key[i], c2 = key[ix];
        bool up = ((i & k) == 0);
        if ((a2 > c2) == up) { key[i] = c2; key[ix] = a2; }
      }
      __syncthreads();
    }
  }
  int tok = (int)(key[t] >> 32);
  idx[(size_t)b*S_ + t] = tok;
  wts[(size_t)b*S_ + t] = __uint_as_float((unsigned)(key[t] & 0xFFFFFFFFu));
  map[(size_t)b*T_ + tok] = t;
}

// -------- fp32 -> bf16 conversion (weights) --------
__global__ __launch_bounds__(256) void k_cvt(const float* __restrict__ s,
    short* __restrict__ d, int n4) {
  int i = blockIdx.x * 256 + threadIdx.x;
  if (i >= n4) return;
  float4 v = ((const float4*)s)[i];
  short4 o;
  o.x = f2bf(v.x); o.y = f2bf(v.y); o.z = f2bf(v.z); o.w = f2bf(v.w);
  ((short4*)d)[i] = o;
}

// -------- LayerNorm (optionally gathering tokens from x via idx) --------
template<bool GATHER>
__global__ __launch_bounds__(256) void k_ln(const float* __restrict__ x,
    const int* __restrict__ idx, float* __restrict__ hbuf,
    short* __restrict__ obf, const float* __restrict__ g,
    const float* __restrict__ beta) {
  __shared__ float red[8];
  int row = blockIdx.x;
  const float* src;
  if (GATHER) {
    int b = row >> 10, k = row & 1023;
    src = x + ((size_t)b*T_ + idx[b*S_ + k]) * C_;
  } else {
    src = hbuf + (size_t)row * C_;
  }
  int t = threadIdx.x;
  float4 v = *(const float4*)(src + t*4);
  float s  = v.x + v.y + v.z + v.w;
  float s2 = v.x*v.x + v.y*v.y + v.z*v.z + v.w*v.w;
  #pragma unroll
  for (int m = 32; m; m >>= 1) { s += __shfl_xor(s, m); s2 += __shfl_xor(s2, m); }
  int w = t >> 6, lane = t & 63;
  if (lane == 0) { red[w] = s; red[w+4] = s2; }
  __syncthreads();
  s  = red[0]+red[1]+red[2]+red[3];
  s2 = red[4]+red[5]+red[6]+red[7];
  float mu = s * (1.f/(float)C_);
  float var = s2 * (1.f/(float)C_) - mu*mu;
  float rs = rsqrtf(var + 1e-5f);
  int c0 = t*4;
  float4 gw = *(const float4*)(g + c0);
  float4 bw = *(const float4*)(beta + c0);
  short4 o;
  o.x = f2bf((v.x-mu)*rs*gw.x + bw.x);
  o.y = f2bf((v.y-mu)*rs*gw.y + bw.y);
  o.z = f2bf((v.z-mu)*rs*gw.z + bw.z);
  o.w = f2bf((v.w-mu)*rs*gw.w + bw.w);
  *(short4*)(obf + (size_t)row*C_ + c0) = o;
  if (GATHER) *(float4*)(hbuf + (size_t)row*C_ + c0) = v;
}

#define EPI_BF16 0
#define EPI_GELU 1
#define EPI_ADD32 2

// branch-free tanh-form GELU (|err| <= ~4e-4): ~8 VALU ops, no erff
__device__ __forceinline__ float gelu_fast(float v) {
  float z = 0.7978845608f * (v + 0.044715f * v * v * v);
  float e = __expf(2.f * z);
  return v - v * __builtin_amdgcn_rcpf(e + 1.f);
}

// ======== k_gemm9: EXACT m97 configuration. 128x128 tile, BK=32, 256 thr,
// 16KB single-buffered LDS (VGPR-capped ~3 blocks/CU; grid oversubscribed
// 2-8x -> cross-block TLP covers the per-tile drain, m114/m102 evidence).
// Schedule: stage -> vmcnt(0)+syncthreads -> 8 ds_read + 16 MFMA -> syncthreads.
// Chunk XOR (row^(row>>2))&3 keeps b128 reads 2-way (free). Verified frag
// math + packed swapped epilogue from rounds 2-11. ========
template<int BM, int BN, int EPI>
__global__ __launch_bounds__(256) void k_gemm9(
    const short* __restrict__ A, int lda,
    const short* __restrict__ Bp, int ldb,
    void* __restrict__ Cp, int ldc,
    const float* __restrict__ bias,
    int nNt, int Ktot) {
  __shared__ short As[BM*32];
  __shared__ short Bs[BN*32];
  // T1: bijective XCD swizzle (m204)
  int nwg = gridDim.x, orig = blockIdx.x;
  int q8 = nwg >> 3, r8 = nwg & 7;
  int xcd = orig & 7, loc = orig >> 3;
  int wg = (xcd < r8 ? xcd*(q8+1) : r8*(q8+1) + (xcd-r8)*q8) + loc;
  int bm = wg / nNt, bn = wg % nNt;
  const short* Ar = A + (size_t)bm*BM*lda;
  const short* Br = Bp + (size_t)bn*BN*ldb;
  constexpr int WM = BM/2, WN = BN/2, FM = WM/16, FN = WN/16;
  int t = threadIdx.x, lane = t & 63, w = t >> 6;
  int wm = w >> 1, wn = w & 1;
  int lr = lane & 15, kq = lane >> 4;
  f32x4 acc[FM][FN] = {};
  for (int k0 = 0; k0 < Ktot; k0 += 32) {
    // stage: rows of 64B = 4 chunks; chunk permuted by (row^(row>>2))&3 so
    // linear LDS + XOR read is ~2-way conflict (free).
    #pragma unroll
    for (int c = 0; c < BM/64; ++c) {
      int ch = c*256 + t;
      int row = ch >> 2, sq = (ch & 3) ^ ((row ^ (row >> 2)) & 3);
      gload_lds16(Ar + (size_t)row*lda + (k0 + sq*8), &As[ch*8]);
    }
    #pragma unroll
    for (int c = 0; c < BN/64; ++c) {
      int ch = c*256 + t;
      int row = ch >> 2, sq = (ch & 3) ^ ((row ^ (row >> 2)) & 3);
      gload_lds16(Br + (size_t)row*ldb + (k0 + sq*8), &Bs[ch*8]);
    }
    asm volatile("s_waitcnt vmcnt(0)" ::: "memory");
    __syncthreads();
    bf16x8 af[FM], bfv[FN];
    #pragma unroll
    for (int j = 0; j < FN; ++j) {
      int rb = wn*WN + j*16 + lr;
      bfv[j] = *(const bf16x8*)&Bs[rb*32 + ((kq ^ ((rb ^ (rb >> 2)) & 3)) << 3)];
    }
    #pragma unroll
    for (int i = 0; i < FM; ++i) {
      int ra = wm*WM + i*16 + lr;
      af[i] = *(const bf16x8*)&As[ra*32 + ((kq ^ ((ra ^ (ra >> 2)) & 3)) << 3)];
    }
    #pragma unroll
    for (int i = 0; i < FM; ++i)
      #pragma unroll
      for (int j = 0; j < FN; ++j)
        acc[i][j] = __builtin_amdgcn_mfma_f32_16x16x32_bf16(bfv[j], af[i], acc[i][j], 0, 0, 0);
    __syncthreads();
  }
  // packed swapped epilogue (layout verified rounds 2-11):
  // C[m = bm*BM + wm*WM + i*16 + lr][n = bn*BN + wn*WN + j*16 + kq*4 + r]
  int mrow0 = bm*BM + wm*WM + lr;
  int ncol0 = bn*BN + wn*WN + (kq << 2);
  #pragma unroll
  for (int i = 0; i < FM; ++i) {
    int row = mrow0 + i*16;
    #pragma unroll
    for (int j = 0; j < FN; ++j) {
      int col = ncol0 + j*16;
      float4 bv = bias ? *(const float4*)(bias + col) : make_float4(0.f,0.f,0.f,0.f);
      float v0 = acc[i][j][0] + bv.x, v1 = acc[i][j][1] + bv.y;
      float v2 = acc[i][j][2] + bv.z, v3 = acc[i][j][3] + bv.w;
      if (EPI == EPI_ADD32) {
        float* Co = (float*)Cp + (size_t)row*ldc + col;
        float4 old = *(float4*)Co;
        old.x += v0; old.y += v1; old.z += v2; old.w += v3;
        *(float4*)Co = old;
      } else {
        if (EPI == EPI_GELU) {
          v0 = gelu_fast(v0); v1 = gelu_fast(v1);
          v2 = gelu_fast(v2); v3 = gelu_fast(v3);
        }
        short4 o; o.x = f2bf(v0); o.y = f2bf(v1); o.z = f2bf(v2); o.w = f2bf(v3);
        *(short4*)((short*)Cp + (size_t)row*ldc + col) = o;
      }
    }
  }
}

// -------- V transpose: qkv[b,s,2C+h*64+d] -> vt[(b*H+h)*64+d][s] --------
__global__ __launch_bounds__(256) void k_vt(const short* __restrict__ qkv,
                                            short* __restrict__ vt) {
  __shared__ short tile[64][65];
  int blk = blockIdx.x;
  int s0 = (blk & 15) << 6;
  int bh = blk >> 4;
  int b = bh >> 4, h = bh & 15;
  const short* src = qkv + (size_t)b*S_*3*C_ + 2*C_ + h*DH_;
  int t = threadIdx.x;
  #pragma unroll
  for (int it = 0; it < 16; ++it) {
    int e = it*256 + t;
    int r = e >> 6, d = e & 63;
    tile[d][r] = src[(size_t)(s0 + r)*3*C_ + d];
  }
  __syncthreads();
  short* dst = vt + (size_t)bh*DH_*S_ + s0;
  #pragma unroll
  for (int it = 0; it < 16; ++it) {
    int e = it*256 + t;
    int d2 = e >> 6, c = e & 63;
    dst[(size_t)d2*S_ + c] = tile[d2][c];
  }
}

// ======== k_fattn v2 (unchanged from round 7, passing) ========
__global__ __launch_bounds__(256, 4) void k_fattn(
    const short* __restrict__ qkv, const short* __restrict__ vt,
    short* __restrict__ attnb) {
  __shared__ short Ks[2][64*64];
  __shared__ short Ps[4][32*72];
  int qt = blockIdx.x;
  int bh = blockIdx.y;
  int b = bh >> 4, h = bh & 15;
  int t = threadIdx.x, lane = t & 63, w = t >> 6;
  int lr = lane & 15, kq = lane >> 4;
  const short* Qbase = qkv + ((size_t)b*S_ + qt*128)*3*C_ + h*DH_;
  const short* Kbase = qkv + (size_t)b*S_*3*C_ + C_ + h*DH_;
  const short* Vtb   = vt + (size_t)bh*DH_*S_;

  short* Qs = &Ks[0][0];
  #pragma unroll
  for (int c = 0; c < 4; ++c) {
    int ch = c*256 + t;
    int row = ch >> 3, sq = (ch & 7) ^ (row & 7);
    gload_lds16(Qbase + (size_t)row*3*C_ + sq*8, &Qs[ch*8]);
  }
  asm volatile("s_waitcnt vmcnt(0)" ::: "memory");
  __builtin_amdgcn_s_barrier();
  bf16x8 qf[2][2];
  #pragma unroll
  for (int ks = 0; ks < 2; ++ks)
    #pragma unroll
    for (int i = 0; i < 2; ++i) {
      int rq = w*32 + i*16 + lr;
      qf[ks][i] = *(const bf16x8*)&Qs[rq*64 + ((((ks<<2)+kq) ^ (rq & 7)) << 3)];
    }
  asm volatile("s_waitcnt lgkmcnt(0)" ::: "memory");
  __builtin_amdgcn_sched_barrier(0);
  __builtin_amdgcn_s_barrier();

  auto stageK = [&](int buf, int jj) {
    #pragma unroll
    for (int c = 0; c < 2; ++c) {
      int ch = c*256 + t;
      int row = ch >> 3, sq = (ch & 7) ^ (row & 7);
      gload_lds16(Kbase + (size_t)(jj*64 + row)*3*C_ + sq*8, &Ks[buf][ch*8]);
    }
  };
  stageK(0, 0);

  f32x4 o[2][4] = {};
  float m_i[2] = {-3.0e38f, -3.0e38f};
  float l_i[2] = {0.f, 0.f};
  short* Pw = &Ps[w][0];
  int NTl = 2*qt + 2;

  for (int jj = 0; jj < NTl; ++jj) {
    int cur = jj & 1;
    asm volatile("s_waitcnt vmcnt(0)" ::: "memory");
    __builtin_amdgcn_s_barrier();
    if (jj + 1 < NTl) stageK(cur ^ 1, jj + 1);

    f32x4 s[2][4] = {};
    #pragma unroll
    for (int ks = 0; ks < 2; ++ks) {
      bf16x8 kf[4];
      #pragma unroll
      for (int j = 0; j < 4; ++j) {
        int rk = j*16 + lr;
        kf[j] = *(const bf16x8*)&Ks[cur][rk*64 + ((((ks<<2)+kq) ^ (rk & 7)) << 3)];
      }
      #pragma unroll
      for (int i = 0; i < 2; ++i)
        #pragma unroll
        for (int j = 0; j < 4; ++j)
          s[i][j] = __builtin_amdgcn_mfma_f32_16x16x32_bf16(kf[j], qf[ks][i], s[i][j], 0, 0, 0);
    }

    bool maskTile = (jj >= 2*qt);
    #pragma unroll
    for (int i = 0; i < 2; ++i) {
      int qrow = qt*128 + w*32 + i*16 + lr;
      float rmax = -3.0e38f;
      #pragma unroll
      for (int j = 0; j < 4; ++j)
        #pragma unroll
        for (int r = 0; r < 4; ++r) {
          int colg = jj*64 + j*16 + (kq<<2) + r;
          float v = s[i][j][r] * 0.125f;
          if (maskTile && colg > qrow) v = -3.0e38f;
          s[i][j][r] = v;
          rmax = fmaxf(rmax, v);
        }
      rmax = fmaxf(rmax, __shfl_xor(rmax, 16));
      rmax = fmaxf(rmax, __shfl_xor(rmax, 32));
      float mnew = fmaxf(m_i[i], rmax);
      float alpha = __expf(m_i[i] - mnew);
      m_i[i] = mnew;
      float rsum = 0.f;
      #pragma unroll
      for (int j = 0; j < 4; ++j)
        #pragma unroll
        for (int r = 0; r < 4; ++r) {
          float pv = __expf(s[i][j][r] - mnew);
          s[i][j][r] = pv;
          rsum += pv;
        }
      rsum += __shfl_xor(rsum, 16);
      rsum += __shfl_xor(rsum, 32);
      l_i[i] = l_i[i]*alpha + rsum;
      #pragma unroll
      for (int jo = 0; jo < 4; ++jo)
        #pragma unroll
        for (int r = 0; r < 4; ++r)
          o[i][jo][r] *= alpha;
    }

    #pragma unroll
    for (int i = 0; i < 2; ++i)
      #pragma unroll
      for (int j = 0; j < 4; ++j) {
        short4 pk;
        pk.x = f2bf(s[i][j][0]); pk.y = f2bf(s[i][j][1]);
        pk.z = f2bf(s[i][j][2]); pk.w = f2bf(s[i][j][3]);
        *(short4*)&Pw[(i*16 + lr)*72 + j*16 + (kq<<2)] = pk;
      }
    asm volatile("s_waitcnt lgkmcnt(0)" ::: "memory");
    __builtin_amdgcn_sched_barrier(0);

    #pragma unroll
    for (int sstep = 0; sstep < 2; ++sstep) {
      bf16x8 pf[2], vf[4];
      #pragma unroll
      for (int i = 0; i < 2; ++i)
        pf[i] = *(const bf16x8*)&Pw[(i*16 + lr)*72 + sstep*32 + (kq<<3)];
      #pragma unroll
      for (int jo = 0; jo < 4; ++jo)
        vf[jo] = *(const bf16x8*)&Vtb[(size_t)(jo*16 + lr)*S_ + jj*64 + sstep*32 + (kq<<3)];
      #pragma unroll
      for (int i = 0; i < 2; ++i)
        #pragma unroll
        for (int jo = 0; jo < 4; ++jo)
          o[i][jo] = __builtin_amdgcn_mfma_f32_16x16x32_bf16(vf[jo], pf[i], o[i][jo], 0, 0, 0);
    }
  }

  #pragma unroll
  for (int i = 0; i < 2; ++i) {
    float inv = 1.f / l_i[i];
    int q = qt*128 + w*32 + i*16 + lr;
    #pragma unroll
    for (int jo = 0; jo < 4; ++jo) {
      int d = jo*16 + (kq<<2);
      short4 ov;
      ov.x = f2bf(o[i][jo][0]*inv); ov.y = f2bf(o[i][jo][1]*inv);
      ov.z = f2bf(o[i][jo][2]*inv); ov.w = f2bf(o[i][jo][3]*inv);
      *(short4*)&attnb[((size_t)b*S_ + q)*C_ + h*DH_ + d] = ov;
    }
  }
}

// -------- fused combine: out = x (+ w*h on selected rows) --------
__global__ __launch_bounds__(256) void k_combine(const float* __restrict__ x,
    const int* __restrict__ map, const float* __restrict__ wts,
    const float* __restrict__ hbuf, float* __restrict__ out) {
  int row = blockIdx.x;              // 0..B*T-1
  int b = row >> 11;                 // T = 2048
  int m = map[row];
  size_t o = (size_t)row*C_ + threadIdx.x*4;
  float4 xv = *(const float4*)(x + o);
  if (m >= 0) {
    float wv = wts[(size_t)b*S_ + m];
    const float* hr = hbuf + ((size_t)b*S_ + m)*C_ + threadIdx.x*4;
    float4 hv = *(const float4*)hr;
    xv.x += wv*hv.x; xv.y += wv*hv.y; xv.z += wv*hv.z; xv.w += wv*hv.w;
  }
  *(float4*)(out + o) = xv;
}

extern "C" void kernel_launch(void* const* d_in, const int* in_sizes, int n_in,
                              void* d_out, int out_size, void* d_ws, size_t ws_size,
                              hipStream_t stream) {
  const float* x     = (const float*)d_in[0];
  const float* wrt   = (const float*)d_in[1];
  const float* ln1w  = (const float*)d_in[2];
  const float* ln1b  = (const float*)d_in[3];
  const float* wqkv  = (const float*)d_in[4];
  const float* bqkv  = (const float*)d_in[5];
  const float* wo    = (const float*)d_in[6];
  const float* bo    = (const float*)d_in[7];
  const float* ln2w  = (const float*)d_in[8];
  const float* ln2b  = (const float*)d_in[9];
  const float* wfc   = (const float*)d_in[10];
  const float* bfc   = (const float*)d_in[11];
  const float* wproj = (const float*)d_in[12];
  const float* bproj = (const float*)d_in[13];
  float* out = (float*)d_out;

  char* p = (char*)d_ws;
  auto alloc = [&](size_t bytes) {
    char* r = p; p += (bytes + 255) & ~(size_t)255; return r;
  };
  float* logits = (float*)alloc((size_t)B_*T_*4);
  int*   idx    = (int*)  alloc((size_t)B_*S_*4);
  float* wts    = (float*)alloc((size_t)B_*S_*4);
  int*   map    = (int*)  alloc((size_t)B_*T_*4);
  float* hbuf   = (float*)alloc((size_t)M_*C_*4);
  short* abuf   = (short*)alloc((size_t)M_*C_*2);
  short* qkvb   = (short*)alloc((size_t)M_*3*C_*2);
  short* vtb    = (short*)alloc((size_t)B_*H_*DH_*S_*2);
  short* attnb  = (short*)alloc((size_t)M_*C_*2);
  short* fcb    = (short*)alloc((size_t)M_*DFF_*2);
  short* wqkvb  = (short*)alloc((size_t)3*C_*C_*2);
  short* wob    = (short*)alloc((size_t)C_*C_*2);
  short* wfcb   = (short*)alloc((size_t)DFF_*C_*2);
  short* wprojb = (short*)alloc((size_t)C_*DFF_*2);
  if (ws_size < (size_t)(p - (char*)d_ws)) return;

  k_cvt<<<dim3(3*C_*C_/4/256), dim3(256), 0, stream>>>(wqkv, wqkvb, 3*C_*C_/4);
  k_cvt<<<dim3(C_*C_/4/256),   dim3(256), 0, stream>>>(wo, wob, C_*C_/4);
  k_cvt<<<dim3(DFF_*C_/4/256), dim3(256), 0, stream>>>(wfc, wfcb, DFF_*C_/4);
  k_cvt<<<dim3(C_*DFF_/4/256), dim3(256), 0, stream>>>(wproj, wprojb, C_*DFF_/4);

  k_router<<<dim3(B_*T_/4), dim3(256), 0, stream>>>(x, wrt, logits);
  k_initmap<<<dim3(B_*T_/4/256), dim3(256), 0, stream>>>(map);
  k_topk<<<dim3(B_), dim3(1024), 0, stream>>>(logits, idx, wts, map);

  k_ln<true><<<dim3(M_), dim3(256), 0, stream>>>(x, idx, hbuf, abuf, ln1w, ln1b);

  // QKV: [8192,1024] @ [3072,1024]^T   grid 64x24 = 1536
  k_gemm9<128,128,EPI_BF16><<<dim3((M_/128)*(3*C_/128)), dim3(256), 0, stream>>>(
      abuf, C_, wqkvb, C_, qkvb, 3*C_, bqkv, 3*C_/128, C_);

  k_vt<<<dim3(B_*H_*(S_/64)), dim3(256), 0, stream>>>(qkvb, vtb);

  // fused causal flash attention
  k_fattn<<<dim3(S_/128, B_*H_), dim3(256), 0, stream>>>(qkvb, vtb, attnb);

  // h += attn @ w_o^T + b_o   grid 64x8 = 512
  k_gemm9<128,128,EPI_ADD32><<<dim3((M_/128)*(C_/128)), dim3(256), 0, stream>>>(
      attnb, C_, wob, C_, hbuf, C_, bo, C_/128, C_);

  k_ln<false><<<dim3(M_), dim3(256), 0, stream>>>(nullptr, nullptr, hbuf, abuf, ln2w, ln2b);

  // fc = gelu(m @ w_fc^T + b_fc)   grid 64x32 = 2048
  k_gemm9<128,128,EPI_GELU><<<dim3((M_/128)*(DFF_/128)), dim3(256), 0, stream>>>(
      abuf, C_, wfcb, C_, fcb, DFF_, bfc, DFF_/128, C_);

  // h += fc @ w_proj^T + b_proj   grid 64x8 = 512
  k_gemm9<128,128,EPI_ADD32><<<dim3((M_/128)*(C_/128)), dim3(256), 0, stream>>>(
      fcb, DFF_, wprojb, DFF_, hbuf, C_, bproj, C_/128, DFF_);

  // fused combine (replaces copy+scatter)
  k_combine<<<dim3(B_*T_), dim3(256), 0, stream>>>(x, map, wts, hbuf, out);
}

// Round 13
// 526.108 us; speedup vs baseline: 1.0297x; 1.0297x over previous
//
#include <hip/hip_runtime.h>
#include <hip/hip_bf16.h>

#define B_ 8
#define T_ 2048
#define C_ 1024
#define S_ 1024      // top_k == reduced sequence length
#define H_ 16
#define DH_ 64
#define DFF_ 4096
#define M_ (B_*S_)   // 8192 rows through the block

typedef __attribute__((ext_vector_type(8))) short bf16x8;
typedef __attribute__((ext_vector_type(4))) float f32x4;

__device__ __forceinline__ short f2bf(float f) {
  __hip_bfloat16 h = __float2bfloat16(f);
  return *reinterpret_cast<short*>(&h);
}
__device__ __forceinline__ float bf2f(short s) {
  __hip_bfloat16 h = *reinterpret_cast<__hip_bfloat16*>(&s);
  return __bfloat162float(h);
}

typedef const __attribute__((address_space(1))) unsigned int* gas_p;
typedef __attribute__((address_space(3))) unsigned int* las_p;
__device__ __forceinline__ void gload_lds16(const void* g, void* l) {
  __builtin_amdgcn_global_load_lds((gas_p)g, (las_p)l, 16, 0, 0);
}

// ------- router logits (also inits inverse map to -1): one wave/token -------
__global__ __launch_bounds__(256) void k_router(const float* __restrict__ x,
    const float* __restrict__ wr, float* __restrict__ logits,
    int* __restrict__ map) {
  int tok = blockIdx.x * 4 + (threadIdx.x >> 6);
  int l = threadIdx.x & 63;
  const float* xr = x + (size_t)tok * C_;
  float s = 0.f;
  #pragma unroll
  for (int j = 0; j < C_/64; ++j) s += xr[l + 64*j] * wr[l + 64*j];
  #pragma unroll
  for (int m = 32; m; m >>= 1) s += __shfl_xor(s, m);
  if (l == 0) { logits[tok] = s; map[tok] = -1; }
}

// ------------- exact top-k via bitonic sort (1 block / batch) -------------
// also writes inverse map: map[b*T + token] = k
__global__ __launch_bounds__(1024) void k_topk(const float* __restrict__ logits,
    int* __restrict__ idx, float* __restrict__ wts, int* __restrict__ map) {
  __shared__ unsigned long long key[2048];
  int b = blockIdx.x, t = threadIdx.x;
  for (int i = t; i < T_; i += 1024) {
    float v = logits[(size_t)b*T_ + i];
    unsigned u = __float_as_uint(v);
    unsigned so = u ^ ((u >> 31) ? 0xFFFFFFFFu : 0x80000000u);
    key[i] = ((unsigned long long)(~so) << 32) | (unsigned)i;
  }
  __syncthreads();
  for (int k = 2; k <= 2048; k <<= 1) {
    for (int j = k >> 1; j > 0; j >>= 1) {
      int i = ((t & ~(j-1)) << 1) | (t & (j-1));
      int ix = i | j;
      unsigned long long a = key[i], c = key[ix];
      bool up = ((i & k) == 0);
      if ((a > c) == up) { key[i] = c; key[ix] = a; }
      __syncthreads();
    }
  }
  unsigned long long a = key[t];
  __syncthreads();
  unsigned i0 = (unsigned)(a & 0xFFFFFFFFu);
  unsigned so = ~(unsigned)(a >> 32);
  unsigned bits = (so & 0x80000000u) ? (so ^ 0x80000000u) : ~so;
  key[t] = ((unsigned long long)i0 << 32) | bits;
  __syncthreads();
  for (int k = 2; k <= 1024; k <<= 1) {
    for (int j = k >> 1; j > 0; j >>= 1) {
      if (t < 512) {
        int i = ((t & ~(j-1)) << 1) | (t & (j-1));
        int ix = i | j;
        unsigned long long a2 = key[i], c2 = key[ix];
        bool up = ((i & k) == 0);
        if ((a2 > c2) == up) { key[i] = c2; key[ix] = a2; }
      }
      __syncthreads();
    }
  }
  int tok = (int)(key[t] >> 32);
  idx[(size_t)b*S_ + t] = tok;
  wts[(size_t)b*S_ + t] = __uint_as_float((unsigned)(key[t] & 0xFFFFFFFFu));
  map[(size_t)b*T_ + tok] = t;
}

// -------- fp32 -> bf16 conversion (weights) --------
__global__ __launch_bounds__(256) void k_cvt(const float* __restrict__ s,
    short* __restrict__ d, int n4) {
  int i = blockIdx.x * 256 + threadIdx.x;
  if (i >= n4) return;
  float4 v = ((const float4*)s)[i];
  short4 o;
  o.x = f2bf(v.x); o.y = f2bf(v.y); o.z = f2bf(v.z); o.w = f2bf(v.w);
  ((short4*)d)[i] = o;
}

// -------- LayerNorm (optionally gathering tokens from x via idx) --------
template<bool GATHER>
__global__ __launch_bounds__(256) void k_ln(const float* __restrict__ x,
    const int* __restrict__ idx, float* __restrict__ hbuf,
    short* __restrict__ obf, const float* __restrict__ g,
    const float* __restrict__ beta) {
  __shared__ float red[8];
  int row = blockIdx.x;
  const float* src;
  if (GATHER) {
    int b = row >> 10, k = row & 1023;
    src = x + ((size_t)b*T_ + idx[b*S_ + k]) * C_;
  } else {
    src = hbuf + (size_t)row * C_;
  }
  int t = threadIdx.x;
  float4 v = *(const float4*)(src + t*4);
  float s  = v.x + v.y + v.z + v.w;
  float s2 = v.x*v.x + v.y*v.y + v.z*v.z + v.w*v.w;
  #pragma unroll
  for (int m = 32; m; m >>= 1) { s += __shfl_xor(s, m); s2 += __shfl_xor(s2, m); }
  int w = t >> 6, lane = t & 63;
  if (lane == 0) { red[w] = s; red[w+4] = s2; }
  __syncthreads();
  s  = red[0]+red[1]+red[2]+red[3];
  s2 = red[4]+red[5]+red[6]+red[7];
  float mu = s * (1.f/(float)C_);
  float var = s2 * (1.f/(float)C_) - mu*mu;
  float rs = rsqrtf(var + 1e-5f);
  int c0 = t*4;
  float4 gw = *(const float4*)(g + c0);
  float4 bw = *(const float4*)(beta + c0);
  short4 o;
  o.x = f2bf((v.x-mu)*rs*gw.x + bw.x);
  o.y = f2bf((v.y-mu)*rs*gw.y + bw.y);
  o.z = f2bf((v.z-mu)*rs*gw.z + bw.z);
  o.w = f2bf((v.w-mu)*rs*gw.w + bw.w);
  *(short4*)(obf + (size_t)row*C_ + c0) = o;
  if (GATHER) *(float4*)(hbuf + (size_t)row*C_ + c0) = v;
}

#define EPI_BF16 0
#define EPI_GELU 1
#define EPI_ADD32 2
#define EPI_QKV  3

// branch-free tanh-form GELU (|err| <= ~4e-4): ~8 VALU ops, no erff
__device__ __forceinline__ float gelu_fast(float v) {
  float z = 0.7978845608f * (v + 0.044715f * v * v * v);
  float e = __expf(2.f * z);
  return v - v * __builtin_amdgcn_rcpf(e + 1.f);
}

// ======== k_gemm7 (round-10 best config): 128xBN, BK=64, 256 thr,
// double-buffered LDS, distance-1 prefetch, single __syncthreads per tile.
// BN=128 -> 64KB LDS, 2 blocks/CU; BN=64 -> 48KB, 3 blocks/CU (TLP probe).
// EPI_QKV: V-column tiles write vtb transposed (deletes k_vt pass). ========
template<int BM, int BN, int EPI>
__global__ __launch_bounds__(256, 2) void k_gemm7(
    const short* __restrict__ A, int lda,
    const short* __restrict__ Bp, int ldb,
    void* __restrict__ Cp, int ldc,
    const float* __restrict__ bias,
    int nNt, int Ktot, short* __restrict__ vtb) {
  constexpr int ACH = BM*64/8/256;
  constexpr int BCH = BN*64/8/256;
  __shared__ short As[2][BM*64];
  __shared__ short Bs[2][BN*64];
  // T1: bijective XCD swizzle (m204)
  int nwg = gridDim.x, orig = blockIdx.x;
  int q8 = nwg >> 3, r8 = nwg & 7;
  int xcd = orig & 7, loc = orig >> 3;
  int wg = (xcd < r8 ? xcd*(q8+1) : r8*(q8+1) + (xcd-r8)*q8) + loc;
  int bm = wg / nNt, bn = wg % nNt;
  const short* Ar = A + (size_t)bm*BM*lda;
  const short* Br = Bp + (size_t)bn*BN*ldb;
  constexpr int WM = BM/2, WN = BN/2, FM = WM/16, FN = WN/16;
  int t = threadIdx.x, lane = t & 63, w = t >> 6;
  int wm = w >> 1, wn = w & 1;
  int lr = lane & 15, kq = lane >> 4;

  auto stage = [&](int buf, int k0) {
    #pragma unroll
    for (int c = 0; c < ACH; ++c) {
      int ch = c*256 + t;
      int row = ch >> 3, sq = (ch & 7) ^ (row & 7);
      gload_lds16(Ar + (size_t)row*lda + (k0 + sq*8), &As[buf][ch*8]);
    }
    #pragma unroll
    for (int c = 0; c < BCH; ++c) {
      int ch = c*256 + t;
      int row = ch >> 3, sq = (ch & 7) ^ (row & 7);
      gload_lds16(Br + (size_t)row*ldb + (k0 + sq*8), &Bs[buf][ch*8]);
    }
  };

  f32x4 acc[FM][FN] = {};
  int NT = Ktot >> 6;
  stage(0, 0);
  __syncthreads();                       // tile 0 landed (vmcnt0+barrier)
  for (int kt = 0; kt < NT; ++kt) {
    int cur = kt & 1;
    if (kt + 1 < NT) stage(cur ^ 1, (kt + 1) << 6);  // prefetch, max distance
    const short* Ab = As[cur];
    const short* Bb = Bs[cur];
    bf16x8 af[2][FM], bfv[2][FN];
    #pragma unroll
    for (int ks = 0; ks < 2; ++ks) {
      #pragma unroll
      for (int i = 0; i < FM; ++i) {
        int ra = wm*WM + i*16 + lr;
        af[ks][i] = *(const bf16x8*)&Ab[ra*64 + ((((ks<<2)+kq) ^ (ra & 7)) << 3)];
      }
      #pragma unroll
      for (int j = 0; j < FN; ++j) {
        int rb = wn*WN + j*16 + lr;
        bfv[ks][j] = *(const bf16x8*)&Bb[rb*64 + ((((ks<<2)+kq) ^ (rb & 7)) << 3)];
      }
    }
    #pragma unroll
    for (int ks = 0; ks < 2; ++ks)
      #pragma unroll
      for (int i = 0; i < FM; ++i)
        #pragma unroll
        for (int j = 0; j < FN; ++j)
          acc[i][j] = __builtin_amdgcn_mfma_f32_16x16x32_bf16(bfv[ks][j], af[ks][i], acc[i][j], 0, 0, 0);
    if (kt + 1 < NT) __syncthreads();    // kt+1 landed; buffers safe to swap
  }
  // packed swapped epilogue (layout verified rounds 2-12):
  // C[m = bm*BM + wm*WM + i*16 + lr][n = bn*BN + wn*WN + j*16 + kq*4 + r]
  bool inV = (EPI == EPI_QKV) && (bn*BN >= 2*C_);  // V tile (2048 tile-aligned)
  int mrow0 = bm*BM + wm*WM + lr;
  int ncol0 = bn*BN + wn*WN + (kq << 2);
  #pragma unroll
  for (int i = 0; i < FM; ++i) {
    int row = mrow0 + i*16;
    #pragma unroll
    for (int j = 0; j < FN; ++j) {
      int col = ncol0 + j*16;
      float4 bv = bias ? *(const float4*)(bias + col) : make_float4(0.f,0.f,0.f,0.f);
      float v0 = acc[i][j][0] + bv.x, v1 = acc[i][j][1] + bv.y;
      float v2 = acc[i][j][2] + bv.z, v3 = acc[i][j][3] + bv.w;
      if (EPI == EPI_ADD32) {
        float* Co = (float*)Cp + (size_t)row*ldc + col;
        float4 old = *(float4*)Co;
        old.x += v0; old.y += v1; old.z += v2; old.w += v3;
        *(float4*)Co = old;
      } else if (EPI == EPI_QKV && inV) {
        // V columns: write transposed to vtb[(b*H+h)*64+d][s]
        int s = row & (S_-1), bb = row >> 10;
        int dg = col - 2*C_;                 // 0..1023; dg%4==0, d&63 <= 60
        short* vp = vtb + (((size_t)(bb*H_ + (dg >> 6))*DH_ + (dg & 63))*S_ + s);
        vp[0]      = f2bf(v0);
        vp[S_]     = f2bf(v1);
        vp[2*S_]   = f2bf(v2);
        vp[3*(size_t)S_] = f2bf(v3);
      } else {
        if (EPI == EPI_GELU) {
          v0 = gelu_fast(v0); v1 = gelu_fast(v1);
          v2 = gelu_fast(v2); v3 = gelu_fast(v3);
        }
        short4 o; o.x = f2bf(v0); o.y = f2bf(v1); o.z = f2bf(v2); o.w = f2bf(v3);
        *(short4*)((short*)Cp + (size_t)row*ldc + col) = o;
      }
    }
  }
}

// ======== k_fattn v2 (unchanged from round 7, passing) ========
__global__ __launch_bounds__(256, 4) void k_fattn(
    const short* __restrict__ qkv, const short* __restrict__ vt,
    short* __restrict__ attnb) {
  __shared__ short Ks[2][64*64];
  __shared__ short Ps[4][32*72];
  int qt = blockIdx.x;
  int bh = blockIdx.y;
  int b = bh >> 4, h = bh & 15;
  int t = threadIdx.x, lane = t & 63, w = t >> 6;
  int lr = lane & 15, kq = lane >> 4;
  const short* Qbase = qkv + ((size_t)b*S_ + qt*128)*3*C_ + h*DH_;
  const short* Kbase = qkv + (size_t)b*S_*3*C_ + C_ + h*DH_;
  const short* Vtb   = vt + (size_t)bh*DH_*S_;

  short* Qs = &Ks[0][0];
  #pragma unroll
  for (int c = 0; c < 4; ++c) {
    int ch = c*256 + t;
    int row = ch >> 3, sq = (ch & 7) ^ (row & 7);
    gload_lds16(Qbase + (size_t)row*3*C_ + sq*8, &Qs[ch*8]);
  }
  asm volatile("s_waitcnt vmcnt(0)" ::: "memory");
  __builtin_amdgcn_s_barrier();
  bf16x8 qf[2][2];
  #pragma unroll
  for (int ks = 0; ks < 2; ++ks)
    #pragma unroll
    for (int i = 0; i < 2; ++i) {
      int rq = w*32 + i*16 + lr;
      qf[ks][i] = *(const bf16x8*)&Qs[rq*64 + ((((ks<<2)+kq) ^ (rq & 7)) << 3)];
    }
  asm volatile("s_waitcnt lgkmcnt(0)" ::: "memory");
  __builtin_amdgcn_sched_barrier(0);
  __builtin_amdgcn_s_barrier();

  auto stageK = [&](int buf, int jj) {
    #pragma unroll
    for (int c = 0; c < 2; ++c) {
      int ch = c*256 + t;
      int row = ch >> 3, sq = (ch & 7) ^ (row & 7);
      gload_lds16(Kbase + (size_t)(jj*64 + row)*3*C_ + sq*8, &Ks[buf][ch*8]);
    }
  };
  stageK(0, 0);

  f32x4 o[2][4] = {};
  float m_i[2] = {-3.0e38f, -3.0e38f};
  float l_i[2] = {0.f, 0.f};
  short* Pw = &Ps[w][0];
  int NTl = 2*qt + 2;

  for (int jj = 0; jj < NTl; ++jj) {
    int cur = jj & 1;
    asm volatile("s_waitcnt vmcnt(0)" ::: "memory");
    __builtin_amdgcn_s_barrier();
    if (jj + 1 < NTl) stageK(cur ^ 1, jj + 1);

    f32x4 s[2][4] = {};
    #pragma unroll
    for (int ks = 0; ks < 2; ++ks) {
      bf16x8 kf[4];
      #pragma unroll
      for (int j = 0; j < 4; ++j) {
        int rk = j*16 + lr;
        kf[j] = *(const bf16x8*)&Ks[cur][rk*64 + ((((ks<<2)+kq) ^ (rk & 7)) << 3)];
      }
      #pragma unroll
      for (int i = 0; i < 2; ++i)
        #pragma unroll
        for (int j = 0; j < 4; ++j)
          s[i][j] = __builtin_amdgcn_mfma_f32_16x16x32_bf16(kf[j], qf[ks][i], s[i][j], 0, 0, 0);
    }

    bool maskTile = (jj >= 2*qt);
    #pragma unroll
    for (int i = 0; i < 2; ++i) {
      int qrow = qt*128 + w*32 + i*16 + lr;
      float rmax = -3.0e38f;
      #pragma unroll
      for (int j = 0; j < 4; ++j)
        #pragma unroll
        for (int r = 0; r < 4; ++r) {
          int colg = jj*64 + j*16 + (kq<<2) + r;
          float v = s[i][j][r] * 0.125f;
          if (maskTile && colg > qrow) v = -3.0e38f;
          s[i][j][r] = v;
          rmax = fmaxf(rmax, v);
        }
      rmax = fmaxf(rmax, __shfl_xor(rmax, 16));
      rmax = fmaxf(rmax, __shfl_xor(rmax, 32));
      float mnew = fmaxf(m_i[i], rmax);
      float alpha = __expf(m_i[i] - mnew);
      m_i[i] = mnew;
      float rsum = 0.f;
      #pragma unroll
      for (int j = 0; j < 4; ++j)
        #pragma unroll
        for (int r = 0; r < 4; ++r) {
          float pv = __expf(s[i][j][r] - mnew);
          s[i][j][r] = pv;
          rsum += pv;
        }
      rsum += __shfl_xor(rsum, 16);
      rsum += __shfl_xor(rsum, 32);
      l_i[i] = l_i[i]*alpha + rsum;
      #pragma unroll
      for (int jo = 0; jo < 4; ++jo)
        #pragma unroll
        for (int r = 0; r < 4; ++r)
          o[i][jo][r] *= alpha;
    }

    #pragma unroll
    for (int i = 0; i < 2; ++i)
      #pragma unroll
      for (int j = 0; j < 4; ++j) {
        short4 pk;
        pk.x = f2bf(s[i][j][0]); pk.y = f2bf(s[i][j][1]);
        pk.z = f2bf(s[i][j][2]); pk.w = f2bf(s[i][j][3]);
        *(short4*)&Pw[(i*16 + lr)*72 + j*16 + (kq<<2)] = pk;
      }
    asm volatile("s_waitcnt lgkmcnt(0)" ::: "memory");
    __builtin_amdgcn_sched_barrier(0);

    #pragma unroll
    for (int sstep = 0; sstep < 2; ++sstep) {
      bf16x8 pf[2], vf[4];
      #pragma unroll
      for (int i = 0; i < 2; ++i)
        pf[i] = *(const bf16x8*)&Pw[(i*16 + lr)*72 + sstep*32 + (kq<<3)];
      #pragma unroll
      for (int jo = 0; jo < 4; ++jo)
        vf[jo] = *(const bf16x8*)&Vtb[(size_t)(jo*16 + lr)*S_ + jj*64 + sstep*32 + (kq<<3)];
      #pragma unroll
      for (int i = 0; i < 2; ++i)
        #pragma unroll
        for (int jo = 0; jo < 4; ++jo)
          o[i][jo] = __builtin_amdgcn_mfma_f32_16x16x32_bf16(vf[jo], pf[i], o[i][jo], 0, 0, 0);
    }
  }

  #pragma unroll
  for (int i = 0; i < 2; ++i) {
    float inv = 1.f / l_i[i];
    int q = qt*128 + w*32 + i*16 + lr;
    #pragma unroll
    for (int jo = 0; jo < 4; ++jo) {
      int d = jo*16 + (kq<<2);
      short4 ov;
      ov.x = f2bf(o[i][jo][0]*inv); ov.y = f2bf(o[i][jo][1]*inv);
      ov.z = f2bf(o[i][jo][2]*inv); ov.w = f2bf(o[i][jo][3]*inv);
      *(short4*)&attnb[((size_t)b*S_ + q)*C_ + h*DH_ + d] = ov;
    }
  }
}

// -------- fused combine: out = x (+ w*h on selected rows) --------
__global__ __launch_bounds__(256) void k_combine(const float* __restrict__ x,
    const int* __restrict__ map, const float* __restrict__ wts,
    const float* __restrict__ hbuf, float* __restrict__ out) {
  int row = blockIdx.x;              // 0..B*T-1
  int b = row >> 11;                 // T = 2048
  int m = map[row];
  size_t o = (size_t)row*C_ + threadIdx.x*4;
  float4 xv = *(const float4*)(x + o);
  if (m >= 0) {
    float wv = wts[(size_t)b*S_ + m];
    const float* hr = hbuf + ((size_t)b*S_ + m)*C_ + threadIdx.x*4;
    float4 hv = *(const float4*)hr;
    xv.x += wv*hv.x; xv.y += wv*hv.y; xv.z += wv*hv.z; xv.w += wv*hv.w;
  }
  *(float4*)(out + o) = xv;
}

extern "C" void kernel_launch(void* const* d_in, const int* in_sizes, int n_in,
                              void* d_out, int out_size, void* d_ws, size_t ws_size,
                              hipStream_t stream) {
  const float* x     = (const float*)d_in[0];
  const float* wrt   = (const float*)d_in[1];
  const float* ln1w  = (const float*)d_in[2];
  const float* ln1b  = (const float*)d_in[3];
  const float* wqkv  = (const float*)d_in[4];
  const float* bqkv  = (const float*)d_in[5];
  const float* wo    = (const float*)d_in[6];
  const float* bo    = (const float*)d_in[7];
  const float* ln2w  = (const float*)d_in[8];
  const float* ln2b  = (const float*)d_in[9];
  const float* wfc   = (const float*)d_in[10];
  const float* bfc   = (const float*)d_in[11];
  const float* wproj = (const float*)d_in[12];
  const float* bproj = (const float*)d_in[13];
  float* out = (float*)d_out;

  char* p = (char*)d_ws;
  auto alloc = [&](size_t bytes) {
    char* r = p; p += (bytes + 255) & ~(size_t)255; return r;
  };
  float* logits = (float*)alloc((size_t)B_*T_*4);
  int*   idx    = (int*)  alloc((size_t)B_*S_*4);
  float* wts    = (float*)alloc((size_t)B_*S_*4);
  int*   map    = (int*)  alloc((size_t)B_*T_*4);
  float* hbuf   = (float*)alloc((size_t)M_*C_*4);
  short* abuf   = (short*)alloc((size_t)M_*C_*2);
  short* qkvb   = (short*)alloc((size_t)M_*3*C_*2);
  short* vtb    = (short*)alloc((size_t)B_*H_*DH_*S_*2);
  short* attnb  = (short*)alloc((size_t)M_*C_*2);
  short* fcb    = (short*)alloc((size_t)M_*DFF_*2);
  short* wqkvb  = (short*)alloc((size_t)3*C_*C_*2);
  short* wob    = (short*)alloc((size_t)C_*C_*2);
  short* wfcb   = (short*)alloc((size_t)DFF_*C_*2);
  short* wprojb = (short*)alloc((size_t)C_*DFF_*2);
  if (ws_size < (size_t)(p - (char*)d_ws)) return;

  k_cvt<<<dim3(3*C_*C_/4/256), dim3(256), 0, stream>>>(wqkv, wqkvb, 3*C_*C_/4);
  k_cvt<<<dim3(C_*C_/4/256),   dim3(256), 0, stream>>>(wo, wob, C_*C_/4);
  k_cvt<<<dim3(DFF_*C_/4/256), dim3(256), 0, stream>>>(wfc, wfcb, DFF_*C_/4);
  k_cvt<<<dim3(C_*DFF_/4/256), dim3(256), 0, stream>>>(wproj, wprojb, C_*DFF_/4);

  k_router<<<dim3(B_*T_/4), dim3(256), 0, stream>>>(x, wrt, logits, map);
  k_topk<<<dim3(B_), dim3(1024), 0, stream>>>(logits, idx, wts, map);

  k_ln<true><<<dim3(M_), dim3(256), 0, stream>>>(x, idx, hbuf, abuf, ln1w, ln1b);

  // QKV: [8192,1024] @ [3072,1024]^T; V tiles write vtb transposed
  k_gemm7<128,128,EPI_QKV><<<dim3((M_/128)*(3*C_/128)), dim3(256), 0, stream>>>(
      abuf, C_, wqkvb, C_, qkvb, 3*C_, bqkv, 3*C_/128, C_, vtb);

  // fused causal flash attention
  k_fattn<<<dim3(S_/128, B_*H_), dim3(256), 0, stream>>>(qkvb, vtb, attnb);

  // h += attn @ w_o^T + b_o   BN=64: grid 64x16 = 1024, 3 blocks/CU
  k_gemm7<128,64,EPI_ADD32><<<dim3((M_/128)*(C_/64)), dim3(256), 0, stream>>>(
      attnb, C_, wob, C_, hbuf, C_, bo, C_/64, C_, nullptr);

  k_ln<false><<<dim3(M_), dim3(256), 0, stream>>>(nullptr, nullptr, hbuf, abuf, ln2w, ln2b);

  // fc = gelu(m @ w_fc^T + b_fc)   grid 64x32 = 2048
  k_gemm7<128,128,EPI_GELU><<<dim3((M_/128)*(DFF_/128)), dim3(256), 0, stream>>>(
      abuf, C_, wfcb, C_, fcb, DFF_, bfc, DFF_/128, C_, nullptr);

  // h += fc @ w_proj^T + b_proj   BN=64: grid 64x16 = 1024, 3 blocks/CU
  k_gemm7<128,64,EPI_ADD32><<<dim3((M_/128)*(C_/64)), dim3(256), 0, stream>>>(
      fcb, DFF_, wprojb, DFF_, hbuf, C_, bproj, C_/64, DFF_, nullptr);

  // fused combine (replaces copy+scatter)
  k_combine<<<dim3(B_*T_), dim3(256), 0, stream>>>(x, map, wts, hbuf, out);
}

// Round 14
// 474.476 us; speedup vs baseline: 1.1417x; 1.1088x over previous
//
#include <hip/hip_runtime.h>
#include <hip/hip_bf16.h>

#define B_ 8
#define T_ 2048
#define C_ 1024
#define S_ 1024      // top_k == reduced sequence length
#define H_ 16
#define DH_ 64
#define DFF_ 4096
#define M_ (B_*S_)   // 8192 rows through the block

typedef __attribute__((ext_vector_type(8))) short bf16x8;
typedef __attribute__((ext_vector_type(4))) float f32x4;

__device__ __forceinline__ short f2bf(float f) {
  __hip_bfloat16 h = __float2bfloat16(f);
  return *reinterpret_cast<short*>(&h);
}
__device__ __forceinline__ float bf2f(short s) {
  __hip_bfloat16 h = *reinterpret_cast<__hip_bfloat16*>(&s);
  return __bfloat162float(h);
}

typedef const __attribute__((address_space(1))) unsigned int* gas_p;
typedef __attribute__((address_space(3))) unsigned int* las_p;
__device__ __forceinline__ void gload_lds16(const void* g, void* l) {
  __builtin_amdgcn_global_load_lds((gas_p)g, (las_p)l, 16, 0, 0);
}

// ------- router logits (also inits inverse map to -1): one wave/token -------
__global__ __launch_bounds__(256) void k_router(const float* __restrict__ x,
    const float* __restrict__ wr, float* __restrict__ logits,
    int* __restrict__ map) {
  int tok = blockIdx.x * 4 + (threadIdx.x >> 6);
  int l = threadIdx.x & 63;
  const float* xr = x + (size_t)tok * C_;
  float s = 0.f;
  #pragma unroll
  for (int j = 0; j < C_/64; ++j) s += xr[l + 64*j] * wr[l + 64*j];
  #pragma unroll
  for (int m = 32; m; m >>= 1) s += __shfl_xor(s, m);
  if (l == 0) { logits[tok] = s; map[tok] = -1; }
}

// ------------- exact top-k via bitonic sort (1 block / batch) -------------
// also writes inverse map: map[b*T + token] = k
__global__ __launch_bounds__(1024) void k_topk(const float* __restrict__ logits,
    int* __restrict__ idx, float* __restrict__ wts, int* __restrict__ map) {
  __shared__ unsigned long long key[2048];
  int b = blockIdx.x, t = threadIdx.x;
  for (int i = t; i < T_; i += 1024) {
    float v = logits[(size_t)b*T_ + i];
    unsigned u = __float_as_uint(v);
    unsigned so = u ^ ((u >> 31) ? 0xFFFFFFFFu : 0x80000000u);
    key[i] = ((unsigned long long)(~so) << 32) | (unsigned)i;
  }
  __syncthreads();
  for (int k = 2; k <= 2048; k <<= 1) {
    for (int j = k >> 1; j > 0; j >>= 1) {
      int i = ((t & ~(j-1)) << 1) | (t & (j-1));
      int ix = i | j;
      unsigned long long a = key[i], c = key[ix];
      bool up = ((i & k) == 0);
      if ((a > c) == up) { key[i] = c; key[ix] = a; }
      __syncthreads();
    }
  }
  unsigned long long a = key[t];
  __syncthreads();
  unsigned i0 = (unsigned)(a & 0xFFFFFFFFu);
  unsigned so = ~(unsigned)(a >> 32);
  unsigned bits = (so & 0x80000000u) ? (so ^ 0x80000000u) : ~so;
  key[t] = ((unsigned long long)i0 << 32) | bits;
  __syncthreads();
  for (int k = 2; k <= 1024; k <<= 1) {
    for (int j = k >> 1; j > 0; j >>= 1) {
      if (t < 512) {
        int i = ((t & ~(j-1)) << 1) | (t & (j-1));
        int ix = i | j;
        unsigned long long a2 = key[i], c2 = key[ix];
        bool up = ((i & k) == 0);
        if ((a2 > c2) == up) { key[i] = c2; key[ix] = a2; }
      }
      __syncthreads();
    }
  }
  int tok = (int)(key[t] >> 32);
  idx[(size_t)b*S_ + t] = tok;
  wts[(size_t)b*S_ + t] = __uint_as_float((unsigned)(key[t] & 0xFFFFFFFFu));
  map[(size_t)b*T_ + tok] = t;
}

// -------- fp32 -> bf16 conversion (weights) --------
__global__ __launch_bounds__(256) void k_cvt(const float* __restrict__ s,
    short* __restrict__ d, int n4) {
  int i = blockIdx.x * 256 + threadIdx.x;
  if (i >= n4) return;
  float4 v = ((const float4*)s)[i];
  short4 o;
  o.x = f2bf(v.x); o.y = f2bf(v.y); o.z = f2bf(v.z); o.w = f2bf(v.w);
  ((short4*)d)[i] = o;
}

// -------- LayerNorm (optionally gathering tokens from x via idx) --------
template<bool GATHER>
__global__ __launch_bounds__(256) void k_ln(const float* __restrict__ x,
    const int* __restrict__ idx, float* __restrict__ hbuf,
    short* __restrict__ obf, const float* __restrict__ g,
    const float* __restrict__ beta) {
  __shared__ float red[8];
  int row = blockIdx.x;
  const float* src;
  if (GATHER) {
    int b = row >> 10, k = row & 1023;
    src = x + ((size_t)b*T_ + idx[b*S_ + k]) * C_;
  } else {
    src = hbuf + (size_t)row * C_;
  }
  int t = threadIdx.x;
  float4 v = *(const float4*)(src + t*4);
  float s  = v.x + v.y + v.z + v.w;
  float s2 = v.x*v.x + v.y*v.y + v.z*v.z + v.w*v.w;
  #pragma unroll
  for (int m = 32; m; m >>= 1) { s += __shfl_xor(s, m); s2 += __shfl_xor(s2, m); }
  int w = t >> 6, lane = t & 63;
  if (lane == 0) { red[w] = s; red[w+4] = s2; }
  __syncthreads();
  s  = red[0]+red[1]+red[2]+red[3];
  s2 = red[4]+red[5]+red[6]+red[7];
  float mu = s * (1.f/(float)C_);
  float var = s2 * (1.f/(float)C_) - mu*mu;
  float rs = rsqrtf(var + 1e-5f);
  int c0 = t*4;
  float4 gw = *(const float4*)(g + c0);
  float4 bw = *(const float4*)(beta + c0);
  short4 o;
  o.x = f2bf((v.x-mu)*rs*gw.x + bw.x);
  o.y = f2bf((v.y-mu)*rs*gw.y + bw.y);
  o.z = f2bf((v.z-mu)*rs*gw.z + bw.z);
  o.w = f2bf((v.w-mu)*rs*gw.w + bw.w);
  *(short4*)(obf + (size_t)row*C_ + c0) = o;
  if (GATHER) *(float4*)(hbuf + (size_t)row*C_ + c0) = v;
}

#define EPI_BF16 0
#define EPI_GELU 1
#define EPI_ADD32 2
#define EPI_QKV  3

// branch-free tanh-form GELU (|err| <= ~4e-4): ~8 VALU ops, no erff
__device__ __forceinline__ float gelu_fast(float v) {
  float z = 0.7978845608f * (v + 0.044715f * v * v * v);
  float e = __expf(2.f * z);
  return v - v * __builtin_amdgcn_rcpf(e + 1.f);
}

// ======== k_gemm7 (round-10 best config): 128x128, BK=64, 256 thr,
// 64KB double-buffered LDS, distance-1 prefetch, single __syncthreads/tile.
// EPI_QKV: V-column tiles write vtb transposed (deletes k_vt pass). ========
template<int BM, int BN, int EPI>
__global__ __launch_bounds__(256, 2) void k_gemm7(
    const short* __restrict__ A, int lda,
    const short* __restrict__ Bp, int ldb,
    void* __restrict__ Cp, int ldc,
    const float* __restrict__ bias,
    int nNt, int Ktot, short* __restrict__ vtb) {
  constexpr int ACH = BM*64/8/256;
  constexpr int BCH = BN*64/8/256;
  __shared__ short As[2][BM*64];
  __shared__ short Bs[2][BN*64];
  // T1: bijective XCD swizzle (m204)
  int nwg = gridDim.x, orig = blockIdx.x;
  int q8 = nwg >> 3, r8 = nwg & 7;
  int xcd = orig & 7, loc = orig >> 3;
  int wg = (xcd < r8 ? xcd*(q8+1) : r8*(q8+1) + (xcd-r8)*q8) + loc;
  int bm = wg / nNt, bn = wg % nNt;
  const short* Ar = A + (size_t)bm*BM*lda;
  const short* Br = Bp + (size_t)bn*BN*ldb;
  constexpr int WM = BM/2, WN = BN/2, FM = WM/16, FN = WN/16;
  int t = threadIdx.x, lane = t & 63, w = t >> 6;
  int wm = w >> 1, wn = w & 1;
  int lr = lane & 15, kq = lane >> 4;

  auto stage = [&](int buf, int k0) {
    #pragma unroll
    for (int c = 0; c < ACH; ++c) {
      int ch = c*256 + t;
      int row = ch >> 3, sq = (ch & 7) ^ (row & 7);
      gload_lds16(Ar + (size_t)row*lda + (k0 + sq*8), &As[buf][ch*8]);
    }
    #pragma unroll
    for (int c = 0; c < BCH; ++c) {
      int ch = c*256 + t;
      int row = ch >> 3, sq = (ch & 7) ^ (row & 7);
      gload_lds16(Br + (size_t)row*ldb + (k0 + sq*8), &Bs[buf][ch*8]);
    }
  };

  f32x4 acc[FM][FN] = {};
  int NT = Ktot >> 6;
  stage(0, 0);
  __syncthreads();                       // tile 0 landed (vmcnt0+barrier)
  for (int kt = 0; kt < NT; ++kt) {
    int cur = kt & 1;
    if (kt + 1 < NT) stage(cur ^ 1, (kt + 1) << 6);  // prefetch, max distance
    const short* Ab = As[cur];
    const short* Bb = Bs[cur];
    bf16x8 af[2][FM], bfv[2][FN];
    #pragma unroll
    for (int ks = 0; ks < 2; ++ks) {
      #pragma unroll
      for (int i = 0; i < FM; ++i) {
        int ra = wm*WM + i*16 + lr;
        af[ks][i] = *(const bf16x8*)&Ab[ra*64 + ((((ks<<2)+kq) ^ (ra & 7)) << 3)];
      }
      #pragma unroll
      for (int j = 0; j < FN; ++j) {
        int rb = wn*WN + j*16 + lr;
        bfv[ks][j] = *(const bf16x8*)&Bb[rb*64 + ((((ks<<2)+kq) ^ (rb & 7)) << 3)];
      }
    }
    #pragma unroll
    for (int ks = 0; ks < 2; ++ks)
      #pragma unroll
      for (int i = 0; i < FM; ++i)
        #pragma unroll
        for (int j = 0; j < FN; ++j)
          acc[i][j] = __builtin_amdgcn_mfma_f32_16x16x32_bf16(bfv[ks][j], af[ks][i], acc[i][j], 0, 0, 0);
    if (kt + 1 < NT) __syncthreads();    // kt+1 landed; buffers safe to swap
  }
  // packed swapped epilogue (layout verified rounds 2-13):
  // C[m = bm*BM + wm*WM + i*16 + lr][n = bn*BN + wn*WN + j*16 + kq*4 + r]
  bool inV = (EPI == EPI_QKV) && (bn*BN >= 2*C_);  // V tile (2048 tile-aligned)
  int mrow0 = bm*BM + wm*WM + lr;
  int ncol0 = bn*BN + wn*WN + (kq << 2);
  #pragma unroll
  for (int i = 0; i < FM; ++i) {
    int row = mrow0 + i*16;
    #pragma unroll
    for (int j = 0; j < FN; ++j) {
      int col = ncol0 + j*16;
      float4 bv = bias ? *(const float4*)(bias + col) : make_float4(0.f,0.f,0.f,0.f);
      float v0 = acc[i][j][0] + bv.x, v1 = acc[i][j][1] + bv.y;
      float v2 = acc[i][j][2] + bv.z, v3 = acc[i][j][3] + bv.w;
      if (EPI == EPI_ADD32) {
        float* Co = (float*)Cp + (size_t)row*ldc + col;
        float4 old = *(float4*)Co;
        old.x += v0; old.y += v1; old.z += v2; old.w += v3;
        *(float4*)Co = old;
      } else if (EPI == EPI_QKV && inV) {
        // V columns: write transposed to vtb[(b*H+h)*64+d][s]
        int s = row & (S_-1), bb = row >> 10;
        int dg = col - 2*C_;                 // 0..1023
        short* vp = vtb + (((size_t)(bb*H_ + (dg >> 6))*DH_ + (dg & 63))*S_ + s);
        vp[0]      = f2bf(v0);
        vp[S_]     = f2bf(v1);
        vp[2*S_]   = f2bf(v2);
        vp[3*(size_t)S_] = f2bf(v3);
      } else {
        if (EPI == EPI_GELU) {
          v0 = gelu_fast(v0); v1 = gelu_fast(v1);
          v2 = gelu_fast(v2); v3 = gelu_fast(v3);
        }
        short4 o; o.x = f2bf(v0); o.y = f2bf(v1); o.z = f2bf(v2); o.w = f2bf(v3);
        *(short4*)((short*)Cp + (size_t)row*ldc + col) = o;
      }
    }
  }
}

// ======== k_fattn v2 (unchanged from round 7, passing) ========
__global__ __launch_bounds__(256, 4) void k_fattn(
    const short* __restrict__ qkv, const short* __restrict__ vt,
    short* __restrict__ attnb) {
  __shared__ short Ks[2][64*64];
  __shared__ short Ps[4][32*72];
  int qt = blockIdx.x;
  int bh = blockIdx.y;
  int b = bh >> 4, h = bh & 15;
  int t = threadIdx.x, lane = t & 63, w = t >> 6;
  int lr = lane & 15, kq = lane >> 4;
  const short* Qbase = qkv + ((size_t)b*S_ + qt*128)*3*C_ + h*DH_;
  const short* Kbase = qkv + (size_t)b*S_*3*C_ + C_ + h*DH_;
  const short* Vtb   = vt + (size_t)bh*DH_*S_;

  short* Qs = &Ks[0][0];
  #pragma unroll
  for (int c = 0; c < 4; ++c) {
    int ch = c*256 + t;
    int row = ch >> 3, sq = (ch & 7) ^ (row & 7);
    gload_lds16(Qbase + (size_t)row*3*C_ + sq*8, &Qs[ch*8]);
  }
  asm volatile("s_waitcnt vmcnt(0)" ::: "memory");
  __builtin_amdgcn_s_barrier();
  bf16x8 qf[2][2];
  #pragma unroll
  for (int ks = 0; ks < 2; ++ks)
    #pragma unroll
    for (int i = 0; i < 2; ++i) {
      int rq = w*32 + i*16 + lr;
      qf[ks][i] = *(const bf16x8*)&Qs[rq*64 + ((((ks<<2)+kq) ^ (rq & 7)) << 3)];
    }
  asm volatile("s_waitcnt lgkmcnt(0)" ::: "memory");
  __builtin_amdgcn_sched_barrier(0);
  __builtin_amdgcn_s_barrier();

  auto stageK = [&](int buf, int jj) {
    #pragma unroll
    for (int c = 0; c < 2; ++c) {
      int ch = c*256 + t;
      int row = ch >> 3, sq = (ch & 7) ^ (row & 7);
      gload_lds16(Kbase + (size_t)(jj*64 + row)*3*C_ + sq*8, &Ks[buf][ch*8]);
    }
  };
  stageK(0, 0);

  f32x4 o[2][4] = {};
  float m_i[2] = {-3.0e38f, -3.0e38f};
  float l_i[2] = {0.f, 0.f};
  short* Pw = &Ps[w][0];
  int NTl = 2*qt + 2;

  for (int jj = 0; jj < NTl; ++jj) {
    int cur = jj & 1;
    asm volatile("s_waitcnt vmcnt(0)" ::: "memory");
    __builtin_amdgcn_s_barrier();
    if (jj + 1 < NTl) stageK(cur ^ 1, jj + 1);

    f32x4 s[2][4] = {};
    #pragma unroll
    for (int ks = 0; ks < 2; ++ks) {
      bf16x8 kf[4];
      #pragma unroll
      for (int j = 0; j < 4; ++j) {
        int rk = j*16 + lr;
        kf[j] = *(const bf16x8*)&Ks[cur][rk*64 + ((((ks<<2)+kq) ^ (rk & 7)) << 3)];
      }
      #pragma unroll
      for (int i = 0; i < 2; ++i)
        #pragma unroll
        for (int j = 0; j < 4; ++j)
          s[i][j] = __builtin_amdgcn_mfma_f32_16x16x32_bf16(kf[j], qf[ks][i], s[i][j], 0, 0, 0);
    }

    bool maskTile = (jj >= 2*qt);
    #pragma unroll
    for (int i = 0; i < 2; ++i) {
      int qrow = qt*128 + w*32 + i*16 + lr;
      float rmax = -3.0e38f;
      #pragma unroll
      for (int j = 0; j < 4; ++j)
        #pragma unroll
        for (int r = 0; r < 4; ++r) {
          int colg = jj*64 + j*16 + (kq<<2) + r;
          float v = s[i][j][r] * 0.125f;
          if (maskTile && colg > qrow) v = -3.0e38f;
          s[i][j][r] = v;
          rmax = fmaxf(rmax, v);
        }
      rmax = fmaxf(rmax, __shfl_xor(rmax, 16));
      rmax = fmaxf(rmax, __shfl_xor(rmax, 32));
      float mnew = fmaxf(m_i[i], rmax);
      float alpha = __expf(m_i[i] - mnew);
      m_i[i] = mnew;
      float rsum = 0.f;
      #pragma unroll
      for (int j = 0; j < 4; ++j)
        #pragma unroll
        for (int r = 0; r < 4; ++r) {
          float pv = __expf(s[i][j][r] - mnew);
          s[i][j][r] = pv;
          rsum += pv;
        }
      rsum += __shfl_xor(rsum, 16);
      rsum += __shfl_xor(rsum, 32);
      l_i[i] = l_i[i]*alpha + rsum;
      #pragma unroll
      for (int jo = 0; jo < 4; ++jo)
        #pragma unroll
        for (int r = 0; r < 4; ++r)
          o[i][jo][r] *= alpha;
    }

    #pragma unroll
    for (int i = 0; i < 2; ++i)
      #pragma unroll
      for (int j = 0; j < 4; ++j) {
        short4 pk;
        pk.x = f2bf(s[i][j][0]); pk.y = f2bf(s[i][j][1]);
        pk.z = f2bf(s[i][j][2]); pk.w = f2bf(s[i][j][3]);
        *(short4*)&Pw[(i*16 + lr)*72 + j*16 + (kq<<2)] = pk;
      }
    asm volatile("s_waitcnt lgkmcnt(0)" ::: "memory");
    __builtin_amdgcn_sched_barrier(0);

    #pragma unroll
    for (int sstep = 0; sstep < 2; ++sstep) {
      bf16x8 pf[2], vf[4];
      #pragma unroll
      for (int i = 0; i < 2; ++i)
        pf[i] = *(const bf16x8*)&Pw[(i*16 + lr)*72 + sstep*32 + (kq<<3)];
      #pragma unroll
      for (int jo = 0; jo < 4; ++jo)
        vf[jo] = *(const bf16x8*)&Vtb[(size_t)(jo*16 + lr)*S_ + jj*64 + sstep*32 + (kq<<3)];
      #pragma unroll
      for (int i = 0; i < 2; ++i)
        #pragma unroll
        for (int jo = 0; jo < 4; ++jo)
          o[i][jo] = __builtin_amdgcn_mfma_f32_16x16x32_bf16(vf[jo], pf[i], o[i][jo], 0, 0, 0);
    }
  }

  #pragma unroll
  for (int i = 0; i < 2; ++i) {
    float inv = 1.f / l_i[i];
    int q = qt*128 + w*32 + i*16 + lr;
    #pragma unroll
    for (int jo = 0; jo < 4; ++jo) {
      int d = jo*16 + (kq<<2);
      short4 ov;
      ov.x = f2bf(o[i][jo][0]*inv); ov.y = f2bf(o[i][jo][1]*inv);
      ov.z = f2bf(o[i][jo][2]*inv); ov.w = f2bf(o[i][jo][3]*inv);
      *(short4*)&attnb[((size_t)b*S_ + q)*C_ + h*DH_ + d] = ov;
    }
  }
}

// -------- fused combine: out = x (+ w*h on selected rows) --------
__global__ __launch_bounds__(256) void k_combine(const float* __restrict__ x,
    const int* __restrict__ map, const float* __restrict__ wts,
    const float* __restrict__ hbuf, float* __restrict__ out) {
  int row = blockIdx.x;              // 0..B*T-1
  int b = row >> 11;                 // T = 2048
  int m = map[row];
  size_t o = (size_t)row*C_ + threadIdx.x*4;
  float4 xv = *(const float4*)(x + o);
  if (m >= 0) {
    float wv = wts[(size_t)b*S_ + m];
    const float* hr = hbuf + ((size_t)b*S_ + m)*C_ + threadIdx.x*4;
    float4 hv = *(const float4*)hr;
    xv.x += wv*hv.x; xv.y += wv*hv.y; xv.z += wv*hv.z; xv.w += wv*hv.w;
  }
  *(float4*)(out + o) = xv;
}

extern "C" void kernel_launch(void* const* d_in, const int* in_sizes, int n_in,
                              void* d_out, int out_size, void* d_ws, size_t ws_size,
                              hipStream_t stream) {
  const float* x     = (const float*)d_in[0];
  const float* wrt   = (const float*)d_in[1];
  const float* ln1w  = (const float*)d_in[2];
  const float* ln1b  = (const float*)d_in[3];
  const float* wqkv  = (const float*)d_in[4];
  const float* bqkv  = (const float*)d_in[5];
  const float* wo    = (const float*)d_in[6];
  const float* bo    = (const float*)d_in[7];
  const float* ln2w  = (const float*)d_in[8];
  const float* ln2b  = (const float*)d_in[9];
  const float* wfc   = (const float*)d_in[10];
  const float* bfc   = (const float*)d_in[11];
  const float* wproj = (const float*)d_in[12];
  const float* bproj = (const float*)d_in[13];
  float* out = (float*)d_out;

  char* p = (char*)d_ws;
  auto alloc = [&](size_t bytes) {
    char* r = p; p += (bytes + 255) & ~(size_t)255; return r;
  };
  float* logits = (float*)alloc((size_t)B_*T_*4);
  int*   idx    = (int*)  alloc((size_t)B_*S_*4);
  float* wts    = (float*)alloc((size_t)B_*S_*4);
  int*   map    = (int*)  alloc((size_t)B_*T_*4);
  float* hbuf   = (float*)alloc((size_t)M_*C_*4);
  short* abuf   = (short*)alloc((size_t)M_*C_*2);
  short* qkvb   = (short*)alloc((size_t)M_*3*C_*2);
  short* vtb    = (short*)alloc((size_t)B_*H_*DH_*S_*2);
  short* attnb  = (short*)alloc((size_t)M_*C_*2);
  short* fcb    = (short*)alloc((size_t)M_*DFF_*2);
  short* wqkvb  = (short*)alloc((size_t)3*C_*C_*2);
  short* wob    = (short*)alloc((size_t)C_*C_*2);
  short* wfcb   = (short*)alloc((size_t)DFF_*C_*2);
  short* wprojb = (short*)alloc((size_t)C_*DFF_*2);
  if (ws_size < (size_t)(p - (char*)d_ws)) return;

  k_cvt<<<dim3(3*C_*C_/4/256), dim3(256), 0, stream>>>(wqkv, wqkvb, 3*C_*C_/4);
  k_cvt<<<dim3(C_*C_/4/256),   dim3(256), 0, stream>>>(wo, wob, C_*C_/4);
  k_cvt<<<dim3(DFF_*C_/4/256), dim3(256), 0, stream>>>(wfc, wfcb, DFF_*C_/4);
  k_cvt<<<dim3(C_*DFF_/4/256), dim3(256), 0, stream>>>(wproj, wprojb, C_*DFF_/4);

  k_router<<<dim3(B_*T_/4), dim3(256), 0, stream>>>(x, wrt, logits, map);
  k_topk<<<dim3(B_), dim3(1024), 0, stream>>>(logits, idx, wts, map);

  k_ln<true><<<dim3(M_), dim3(256), 0, stream>>>(x, idx, hbuf, abuf, ln1w, ln1b);

  // QKV: [8192,1024] @ [3072,1024]^T; V tiles write vtb transposed
  k_gemm7<128,128,EPI_QKV><<<dim3((M_/128)*(3*C_/128)), dim3(256), 0, stream>>>(
      abuf, C_, wqkvb, C_, qkvb, 3*C_, bqkv, 3*C_/128, C_, vtb);

  // fused causal flash attention
  k_fattn<<<dim3(S_/128, B_*H_), dim3(256), 0, stream>>>(qkvb, vtb, attnb);

  // h += attn @ w_o^T + b_o   grid 64x8 = 512 (round-10 config)
  k_gemm7<128,128,EPI_ADD32><<<dim3((M_/128)*(C_/128)), dim3(256), 0, stream>>>(
      attnb, C_, wob, C_, hbuf, C_, bo, C_/128, C_, nullptr);

  k_ln<false><<<dim3(M_), dim3(256), 0, stream>>>(nullptr, nullptr, hbuf, abuf, ln2w, ln2b);

  // fc = gelu(m @ w_fc^T + b_fc)   grid 64x32 = 2048
  k_gemm7<128,128,EPI_GELU><<<dim3((M_/128)*(DFF_/128)), dim3(256), 0, stream>>>(
      abuf, C_, wfcb, C_, fcb, DFF_, bfc, DFF_/128, C_, nullptr);

  // h += fc @ w_proj^T + b_proj   grid 64x8 = 512 (round-10 config)
  k_gemm7<128,128,EPI_ADD32><<<dim3((M_/128)*(C_/128)), dim3(256), 0, stream>>>(
      fcb, DFF_, wprojb, DFF_, hbuf, C_, bproj, C_/128, DFF_, nullptr);

  // fused combine (replaces copy+scatter)
  k_combine<<<dim3(B_*T_), dim3(256), 0, stream>>>(x, map, wts, hbuf, out);
}

// Round 15
// 464.652 us; speedup vs baseline: 1.1659x; 1.0211x over previous
//
#include <hip/hip_runtime.h>
#include <hip/hip_bf16.h>

#define B_ 8
#define T_ 2048
#define C_ 1024
#define S_ 1024      // top_k == reduced sequence length
#define H_ 16
#define DH_ 64
#define DFF_ 4096
#define M_ (B_*S_)   // 8192 rows through the block

typedef __attribute__((ext_vector_type(8))) short bf16x8;
typedef __attribute__((ext_vector_type(4))) float f32x4;

__device__ __forceinline__ short f2bf(float f) {
  __hip_bfloat16 h = __float2bfloat16(f);
  return *reinterpret_cast<short*>(&h);
}
__device__ __forceinline__ float bf2f(short s) {
  __hip_bfloat16 h = *reinterpret_cast<__hip_bfloat16*>(&s);
  return __bfloat162float(h);
}

typedef const __attribute__((address_space(1))) unsigned int* gas_p;
typedef __attribute__((address_space(3))) unsigned int* las_p;
__device__ __forceinline__ void gload_lds16(const void* g, void* l) {
  __builtin_amdgcn_global_load_lds((gas_p)g, (las_p)l, 16, 0, 0);
}

// ======== k_prep: fused weight-cvt x4 + router logits + map init ========
// Regions by blockIdx (all independent, wave-uniform branch):
//  [0,3072)      cvt wqkv   (3*C*C/4   = 3072*256 float4)
//  [3072,4096)   cvt wo     (C*C/4     = 1024*256)
//  [4096,8192)   cvt wfc    (DFF*C/4   = 4096*256)
//  [8192,12288)  cvt wproj  (C*DFF/4   = 4096*256)
//  [12288,16384) router: 4 tokens/block (wave each) + map[tok] = -1
__global__ __launch_bounds__(256) void k_prep(
    const float* __restrict__ wqkv, short* __restrict__ wqkvb,
    const float* __restrict__ wo,   short* __restrict__ wob,
    const float* __restrict__ wfc,  short* __restrict__ wfcb,
    const float* __restrict__ wproj,short* __restrict__ wprojb,
    const float* __restrict__ x,    const float* __restrict__ wr,
    float* __restrict__ logits, int* __restrict__ map) {
  int bid = blockIdx.x, t = threadIdx.x;
  const float* src; short* dst; int i;
  if (bid < 12288) {
    if (bid < 3072)      { src = wqkv;  dst = wqkvb;  i = bid*256 + t; }
    else if (bid < 4096) { src = wo;    dst = wob;    i = (bid-3072)*256 + t; }
    else if (bid < 8192) { src = wfc;   dst = wfcb;   i = (bid-4096)*256 + t; }
    else                 { src = wproj; dst = wprojb; i = (bid-8192)*256 + t; }
    float4 v = ((const float4*)src)[i];
    short4 o;
    o.x = f2bf(v.x); o.y = f2bf(v.y); o.z = f2bf(v.z); o.w = f2bf(v.w);
    ((short4*)dst)[i] = o;
  } else {
    int tok = (bid - 12288)*4 + (t >> 6);
    int l = t & 63;
    const float* xr = x + (size_t)tok * C_;
    float s = 0.f;
    #pragma unroll
    for (int j = 0; j < C_/64; ++j) s += xr[l + 64*j] * wr[l + 64*j];
    #pragma unroll
    for (int m = 32; m; m >>= 1) s += __shfl_xor(s, m);
    if (l == 0) { logits[tok] = s; map[tok] = -1; }
  }
}

// ------------- exact top-k via bitonic sort (1 block / batch) -------------
// also writes inverse map: map[b*T + token] = k
__global__ __launch_bounds__(1024) void k_topk(const float* __restrict__ logits,
    int* __restrict__ idx, float* __restrict__ wts, int* __restrict__ map) {
  __shared__ unsigned long long key[2048];
  int b = blockIdx.x, t = threadIdx.x;
  for (int i = t; i < T_; i += 1024) {
    float v = logits[(size_t)b*T_ + i];
    unsigned u = __float_as_uint(v);
    unsigned so = u ^ ((u >> 31) ? 0xFFFFFFFFu : 0x80000000u);
    key[i] = ((unsigned long long)(~so) << 32) | (unsigned)i;
  }
  __syncthreads();
  for (int k = 2; k <= 2048; k <<= 1) {
    for (int j = k >> 1; j > 0; j >>= 1) {
      int i = ((t & ~(j-1)) << 1) | (t & (j-1));
      int ix = i | j;
      unsigned long long a = key[i], c = key[ix];
      bool up = ((i & k) == 0);
      if ((a > c) == up) { key[i] = c; key[ix] = a; }
      __syncthreads();
    }
  }
  unsigned long long a = key[t];
  __syncthreads();
  unsigned i0 = (unsigned)(a & 0xFFFFFFFFu);
  unsigned so = ~(unsigned)(a >> 32);
  unsigned bits = (so & 0x80000000u) ? (so ^ 0x80000000u) : ~so;
  key[t] = ((unsigned long long)i0 << 32) | bits;
  __syncthreads();
  for (int k = 2; k <= 1024; k <<= 1) {
    for (int j = k >> 1; j > 0; j >>= 1) {
      if (t < 512) {
        int i = ((t & ~(j-1)) << 1) | (t & (j-1));
        int ix = i | j;
        unsigned long long a2 = key[i], c2 = key[ix];
        bool up = ((i & k) == 0);
        if ((a2 > c2) == up) { key[i] = c2; key[ix] = a2; }
      }
      __syncthreads();
    }
  }
  int tok = (int)(key[t] >> 32);
  idx[(size_t)b*S_ + t] = tok;
  wts[(size_t)b*S_ + t] = __uint_as_float((unsigned)(key[t] & 0xFFFFFFFFu));
  map[(size_t)b*T_ + tok] = t;
}

// -------- LayerNorm (optionally gathering tokens from x via idx) --------
template<bool GATHER>
__global__ __launch_bounds__(256) void k_ln(const float* __restrict__ x,
    const int* __restrict__ idx, float* __restrict__ hbuf,
    short* __restrict__ obf, const float* __restrict__ g,
    const float* __restrict__ beta) {
  __shared__ float red[8];
  int row = blockIdx.x;
  const float* src;
  if (GATHER) {
    int b = row >> 10, k = row & 1023;
    src = x + ((size_t)b*T_ + idx[b*S_ + k]) * C_;
  } else {
    src = hbuf + (size_t)row * C_;
  }
  int t = threadIdx.x;
  float4 v = *(const float4*)(src + t*4);
  float s  = v.x + v.y + v.z + v.w;
  float s2 = v.x*v.x + v.y*v.y + v.z*v.z + v.w*v.w;
  #pragma unroll
  for (int m = 32; m; m >>= 1) { s += __shfl_xor(s, m); s2 += __shfl_xor(s2, m); }
  int w = t >> 6, lane = t & 63;
  if (lane == 0) { red[w] = s; red[w+4] = s2; }
  __syncthreads();
  s  = red[0]+red[1]+red[2]+red[3];
  s2 = red[4]+red[5]+red[6]+red[7];
  float mu = s * (1.f/(float)C_);
  float var = s2 * (1.f/(float)C_) - mu*mu;
  float rs = rsqrtf(var + 1e-5f);
  int c0 = t*4;
  float4 gw = *(const float4*)(g + c0);
  float4 bw = *(const float4*)(beta + c0);
  short4 o;
  o.x = f2bf((v.x-mu)*rs*gw.x + bw.x);
  o.y = f2bf((v.y-mu)*rs*gw.y + bw.y);
  o.z = f2bf((v.z-mu)*rs*gw.z + bw.z);
  o.w = f2bf((v.w-mu)*rs*gw.w + bw.w);
  *(short4*)(obf + (size_t)row*C_ + c0) = o;
  if (GATHER) *(float4*)(hbuf + (size_t)row*C_ + c0) = v;
}

#define EPI_BF16 0
#define EPI_GELU 1
#define EPI_ADD32 2
#define EPI_QKV  3

// branch-free tanh-form GELU (|err| <= ~4e-4): ~8 VALU ops, no erff
__device__ __forceinline__ float gelu_fast(float v) {
  float z = 0.7978845608f * (v + 0.044715f * v * v * v);
  float e = __expf(2.f * z);
  return v - v * __builtin_amdgcn_rcpf(e + 1.f);
}

// ======== k_gemm7 (round-10/14 best config): 128x128, BK=64, 256 thr,
// 64KB double-buffered LDS, distance-1 prefetch, single __syncthreads/tile.
// EPI_QKV: V-column tiles write vtb transposed (deletes k_vt pass). ========
template<int BM, int BN, int EPI>
__global__ __launch_bounds__(256, 2) void k_gemm7(
    const short* __restrict__ A, int lda,
    const short* __restrict__ Bp, int ldb,
    void* __restrict__ Cp, int ldc,
    const float* __restrict__ bias,
    int nNt, int Ktot, short* __restrict__ vtb) {
  constexpr int ACH = BM*64/8/256;
  constexpr int BCH = BN*64/8/256;
  __shared__ short As[2][BM*64];
  __shared__ short Bs[2][BN*64];
  // T1: bijective XCD swizzle (m204)
  int nwg = gridDim.x, orig = blockIdx.x;
  int q8 = nwg >> 3, r8 = nwg & 7;
  int xcd = orig & 7, loc = orig >> 3;
  int wg = (xcd < r8 ? xcd*(q8+1) : r8*(q8+1) + (xcd-r8)*q8) + loc;
  int bm = wg / nNt, bn = wg % nNt;
  const short* Ar = A + (size_t)bm*BM*lda;
  const short* Br = Bp + (size_t)bn*BN*ldb;
  constexpr int WM = BM/2, WN = BN/2, FM = WM/16, FN = WN/16;
  int t = threadIdx.x, lane = t & 63, w = t >> 6;
  int wm = w >> 1, wn = w & 1;
  int lr = lane & 15, kq = lane >> 4;

  auto stage = [&](int buf, int k0) {
    #pragma unroll
    for (int c = 0; c < ACH; ++c) {
      int ch = c*256 + t;
      int row = ch >> 3, sq = (ch & 7) ^ (row & 7);
      gload_lds16(Ar + (size_t)row*lda + (k0 + sq*8), &As[buf][ch*8]);
    }
    #pragma unroll
    for (int c = 0; c < BCH; ++c) {
      int ch = c*256 + t;
      int row = ch >> 3, sq = (ch & 7) ^ (row & 7);
      gload_lds16(Br + (size_t)row*ldb + (k0 + sq*8), &Bs[buf][ch*8]);
    }
  };

  f32x4 acc[FM][FN] = {};
  int NT = Ktot >> 6;
  stage(0, 0);
  __syncthreads();                       // tile 0 landed (vmcnt0+barrier)
  for (int kt = 0; kt < NT; ++kt) {
    int cur = kt & 1;
    if (kt + 1 < NT) stage(cur ^ 1, (kt + 1) << 6);  // prefetch, max distance
    const short* Ab = As[cur];
    const short* Bb = Bs[cur];
    bf16x8 af[2][FM], bfv[2][FN];
    #pragma unroll
    for (int ks = 0; ks < 2; ++ks) {
      #pragma unroll
      for (int i = 0; i < FM; ++i) {
        int ra = wm*WM + i*16 + lr;
        af[ks][i] = *(const bf16x8*)&Ab[ra*64 + ((((ks<<2)+kq) ^ (ra & 7)) << 3)];
      }
      #pragma unroll
      for (int j = 0; j < FN; ++j) {
        int rb = wn*WN + j*16 + lr;
        bfv[ks][j] = *(const bf16x8*)&Bb[rb*64 + ((((ks<<2)+kq) ^ (rb & 7)) << 3)];
      }
    }
    #pragma unroll
    for (int ks = 0; ks < 2; ++ks)
      #pragma unroll
      for (int i = 0; i < FM; ++i)
        #pragma unroll
        for (int j = 0; j < FN; ++j)
          acc[i][j] = __builtin_amdgcn_mfma_f32_16x16x32_bf16(bfv[ks][j], af[ks][i], acc[i][j], 0, 0, 0);
    if (kt + 1 < NT) __syncthreads();    // kt+1 landed; buffers safe to swap
  }
  // packed swapped epilogue (layout verified rounds 2-14):
  // C[m = bm*BM + wm*WM + i*16 + lr][n = bn*BN + wn*WN + j*16 + kq*4 + r]
  bool inV = (EPI == EPI_QKV) && (bn*BN >= 2*C_);  // V tile (2048 tile-aligned)
  int mrow0 = bm*BM + wm*WM + lr;
  int ncol0 = bn*BN + wn*WN + (kq << 2);
  #pragma unroll
  for (int i = 0; i < FM; ++i) {
    int row = mrow0 + i*16;
    #pragma unroll
    for (int j = 0; j < FN; ++j) {
      int col = ncol0 + j*16;
      float4 bv = bias ? *(const float4*)(bias + col) : make_float4(0.f,0.f,0.f,0.f);
      float v0 = acc[i][j][0] + bv.x, v1 = acc[i][j][1] + bv.y;
      float v2 = acc[i][j][2] + bv.z, v3 = acc[i][j][3] + bv.w;
      if (EPI == EPI_ADD32) {
        float* Co = (float*)Cp + (size_t)row*ldc + col;
        float4 old = *(float4*)Co;
        old.x += v0; old.y += v1; old.z += v2; old.w += v3;
        *(float4*)Co = old;
      } else if (EPI == EPI_QKV && inV) {
        // V columns: write transposed to vtb[(b*H+h)*64+d][s]
        int s = row & (S_-1), bb = row >> 10;
        int dg = col - 2*C_;                 // 0..1023
        short* vp = vtb + (((size_t)(bb*H_ + (dg >> 6))*DH_ + (dg & 63))*S_ + s);
        vp[0]      = f2bf(v0);
        vp[S_]     = f2bf(v1);
        vp[2*S_]   = f2bf(v2);
        vp[3*(size_t)S_] = f2bf(v3);
      } else {
        if (EPI == EPI_GELU) {
          v0 = gelu_fast(v0); v1 = gelu_fast(v1);
          v2 = gelu_fast(v2); v3 = gelu_fast(v3);
        }
        short4 o; o.x = f2bf(v0); o.y = f2bf(v1); o.z = f2bf(v2); o.w = f2bf(v3);
        *(short4*)((short*)Cp + (size_t)row*ldc + col) = o;
      }
    }
  }
}

// ======== k_fattn v2 (unchanged from round 7, passing) ========
__global__ __launch_bounds__(256, 4) void k_fattn(
    const short* __restrict__ qkv, const short* __restrict__ vt,
    short* __restrict__ attnb) {
  __shared__ short Ks[2][64*64];
  __shared__ short Ps[4][32*72];
  int qt = blockIdx.x;
  int bh = blockIdx.y;
  int b = bh >> 4, h = bh & 15;
  int t = threadIdx.x, lane = t & 63, w = t >> 6;
  int lr = lane & 15, kq = lane >> 4;
  const short* Qbase = qkv + ((size_t)b*S_ + qt*128)*3*C_ + h*DH_;
  const short* Kbase = qkv + (size_t)b*S_*3*C_ + C_ + h*DH_;
  const short* Vtb   = vt + (size_t)bh*DH_*S_;

  short* Qs = &Ks[0][0];
  #pragma unroll
  for (int c = 0; c < 4; ++c) {
    int ch = c*256 + t;
    int row = ch >> 3, sq = (ch & 7) ^ (row & 7);
    gload_lds16(Qbase + (size_t)row*3*C_ + sq*8, &Qs[ch*8]);
  }
  asm volatile("s_waitcnt vmcnt(0)" ::: "memory");
  __builtin_amdgcn_s_barrier();
  bf16x8 qf[2][2];
  #pragma unroll
  for (int ks = 0; ks < 2; ++ks)
    #pragma unroll
    for (int i = 0; i < 2; ++i) {
      int rq = w*32 + i*16 + lr;
      qf[ks][i] = *(const bf16x8*)&Qs[rq*64 + ((((ks<<2)+kq) ^ (rq & 7)) << 3)];
    }
  asm volatile("s_waitcnt lgkmcnt(0)" ::: "memory");
  __builtin_amdgcn_sched_barrier(0);
  __builtin_amdgcn_s_barrier();

  auto stageK = [&](int buf, int jj) {
    #pragma unroll
    for (int c = 0; c < 2; ++c) {
      int ch = c*256 + t;
      int row = ch >> 3, sq = (ch & 7) ^ (row & 7);
      gload_lds16(Kbase + (size_t)(jj*64 + row)*3*C_ + sq*8, &Ks[buf][ch*8]);
    }
  };
  stageK(0, 0);

  f32x4 o[2][4] = {};
  float m_i[2] = {-3.0e38f, -3.0e38f};
  float l_i[2] = {0.f, 0.f};
  short* Pw = &Ps[w][0];
  int NTl = 2*qt + 2;

  for (int jj = 0; jj < NTl; ++jj) {
    int cur = jj & 1;
    asm volatile("s_waitcnt vmcnt(0)" ::: "memory");
    __builtin_amdgcn_s_barrier();
    if (jj + 1 < NTl) stageK(cur ^ 1, jj + 1);

    f32x4 s[2][4] = {};
    #pragma unroll
    for (int ks = 0; ks < 2; ++ks) {
      bf16x8 kf[4];
      #pragma unroll
      for (int j = 0; j < 4; ++j) {
        int rk = j*16 + lr;
        kf[j] = *(const bf16x8*)&Ks[cur][rk*64 + ((((ks<<2)+kq) ^ (rk & 7)) << 3)];
      }
      #pragma unroll
      for (int i = 0; i < 2; ++i)
        #pragma unroll
        for (int j = 0; j < 4; ++j)
          s[i][j] = __builtin_amdgcn_mfma_f32_16x16x32_bf16(kf[j], qf[ks][i], s[i][j], 0, 0, 0);
    }

    bool maskTile = (jj >= 2*qt);
    #pragma unroll
    for (int i = 0; i < 2; ++i) {
      int qrow = qt*128 + w*32 + i*16 + lr;
      float rmax = -3.0e38f;
      #pragma unroll
      for (int j = 0; j < 4; ++j)
        #pragma unroll
        for (int r = 0; r < 4; ++r) {
          int colg = jj*64 + j*16 + (kq<<2) + r;
          float v = s[i][j][r] * 0.125f;
          if (maskTile && colg > qrow) v = -3.0e38f;
          s[i][j][r] = v;
          rmax = fmaxf(rmax, v);
        }
      rmax = fmaxf(rmax, __shfl_xor(rmax, 16));
      rmax = fmaxf(rmax, __shfl_xor(rmax, 32));
      float mnew = fmaxf(m_i[i], rmax);
      float alpha = __expf(m_i[i] - mnew);
      m_i[i] = mnew;
      float rsum = 0.f;
      #pragma unroll
      for (int j = 0; j < 4; ++j)
        #pragma unroll
        for (int r = 0; r < 4; ++r) {
          float pv = __expf(s[i][j][r] - mnew);
          s[i][j][r] = pv;
          rsum += pv;
        }
      rsum += __shfl_xor(rsum, 16);
      rsum += __shfl_xor(rsum, 32);
      l_i[i] = l_i[i]*alpha + rsum;
      #pragma unroll
      for (int jo = 0; jo < 4; ++jo)
        #pragma unroll
        for (int r = 0; r < 4; ++r)
          o[i][jo][r] *= alpha;
    }

    #pragma unroll
    for (int i = 0; i < 2; ++i)
      #pragma unroll
      for (int j = 0; j < 4; ++j) {
        short4 pk;
        pk.x = f2bf(s[i][j][0]); pk.y = f2bf(s[i][j][1]);
        pk.z = f2bf(s[i][j][2]); pk.w = f2bf(s[i][j][3]);
        *(short4*)&Pw[(i*16 + lr)*72 + j*16 + (kq<<2)] = pk;
      }
    asm volatile("s_waitcnt lgkmcnt(0)" ::: "memory");
    __builtin_amdgcn_sched_barrier(0);

    #pragma unroll
    for (int sstep = 0; sstep < 2; ++sstep) {
      bf16x8 pf[2], vf[4];
      #pragma unroll
      for (int i = 0; i < 2; ++i)
        pf[i] = *(const bf16x8*)&Pw[(i*16 + lr)*72 + sstep*32 + (kq<<3)];
      #pragma unroll
      for (int jo = 0; jo < 4; ++jo)
        vf[jo] = *(const bf16x8*)&Vtb[(size_t)(jo*16 + lr)*S_ + jj*64 + sstep*32 + (kq<<3)];
      #pragma unroll
      for (int i = 0; i < 2; ++i)
        #pragma unroll
        for (int jo = 0; jo < 4; ++jo)
          o[i][jo] = __builtin_amdgcn_mfma_f32_16x16x32_bf16(vf[jo], pf[i], o[i][jo], 0, 0, 0);
    }
  }

  #pragma unroll
  for (int i = 0; i < 2; ++i) {
    float inv = 1.f / l_i[i];
    int q = qt*128 + w*32 + i*16 + lr;
    #pragma unroll
    for (int jo = 0; jo < 4; ++jo) {
      int d = jo*16 + (kq<<2);
      short4 ov;
      ov.x = f2bf(o[i][jo][0]*inv); ov.y = f2bf(o[i][jo][1]*inv);
      ov.z = f2bf(o[i][jo][2]*inv); ov.w = f2bf(o[i][jo][3]*inv);
      *(short4*)&attnb[((size_t)b*S_ + q)*C_ + h*DH_ + d] = ov;
    }
  }
}

// -------- fused combine: out = x (+ w*h on selected rows) --------
__global__ __launch_bounds__(256) void k_combine(const float* __restrict__ x,
    const int* __restrict__ map, const float* __restrict__ wts,
    const float* __restrict__ hbuf, float* __restrict__ out) {
  int row = blockIdx.x;              // 0..B*T-1
  int b = row >> 11;                 // T = 2048
  int m = map[row];
  size_t o = (size_t)row*C_ + threadIdx.x*4;
  float4 xv = *(const float4*)(x + o);
  if (m >= 0) {
    float wv = wts[(size_t)b*S_ + m];
    const float* hr = hbuf + ((size_t)b*S_ + m)*C_ + threadIdx.x*4;
    float4 hv = *(const float4*)hr;
    xv.x += wv*hv.x; xv.y += wv*hv.y; xv.z += wv*hv.z; xv.w += wv*hv.w;
  }
  *(float4*)(out + o) = xv;
}

extern "C" void kernel_launch(void* const* d_in, const int* in_sizes, int n_in,
                              void* d_out, int out_size, void* d_ws, size_t ws_size,
                              hipStream_t stream) {
  const float* x     = (const float*)d_in[0];
  const float* wrt   = (const float*)d_in[1];
  const float* ln1w  = (const float*)d_in[2];
  const float* ln1b  = (const float*)d_in[3];
  const float* wqkv  = (const float*)d_in[4];
  const float* bqkv  = (const float*)d_in[5];
  const float* wo    = (const float*)d_in[6];
  const float* bo    = (const float*)d_in[7];
  const float* ln2w  = (const float*)d_in[8];
  const float* ln2b  = (const float*)d_in[9];
  const float* wfc   = (const float*)d_in[10];
  const float* bfc   = (const float*)d_in[11];
  const float* wproj = (const float*)d_in[12];
  const float* bproj = (const float*)d_in[13];
  float* out = (float*)d_out;

  char* p = (char*)d_ws;
  auto alloc = [&](size_t bytes) {
    char* r = p; p += (bytes + 255) & ~(size_t)255; return r;
  };
  float* logits = (float*)alloc((size_t)B_*T_*4);
  int*   idx    = (int*)  alloc((size_t)B_*S_*4);
  float* wts    = (float*)alloc((size_t)B_*S_*4);
  int*   map    = (int*)  alloc((size_t)B_*T_*4);
  float* hbuf   = (float*)alloc((size_t)M_*C_*4);
  short* abuf   = (short*)alloc((size_t)M_*C_*2);
  short* qkvb   = (short*)alloc((size_t)M_*3*C_*2);
  short* vtb    = (short*)alloc((size_t)B_*H_*DH_*S_*2);
  short* attnb  = (short*)alloc((size_t)M_*C_*2);
  short* fcb    = (short*)alloc((size_t)M_*DFF_*2);
  short* wqkvb  = (short*)alloc((size_t)3*C_*C_*2);
  short* wob    = (short*)alloc((size_t)C_*C_*2);
  short* wfcb   = (short*)alloc((size_t)DFF_*C_*2);
  short* wprojb = (short*)alloc((size_t)C_*DFF_*2);
  if (ws_size < (size_t)(p - (char*)d_ws)) return;

  // fused prep: weight conversions + router logits + map init
  k_prep<<<dim3(16384), dim3(256), 0, stream>>>(
      wqkv, wqkvb, wo, wob, wfc, wfcb, wproj, wprojb, x, wrt, logits, map);

  k_topk<<<dim3(B_), dim3(1024), 0, stream>>>(logits, idx, wts, map);

  k_ln<true><<<dim3(M_), dim3(256), 0, stream>>>(x, idx, hbuf, abuf, ln1w, ln1b);

  // QKV: [8192,1024] @ [3072,1024]^T; V tiles write vtb transposed
  k_gemm7<128,128,EPI_QKV><<<dim3((M_/128)*(3*C_/128)), dim3(256), 0, stream>>>(
      abuf, C_, wqkvb, C_, qkvb, 3*C_, bqkv, 3*C_/128, C_, vtb);

  // fused causal flash attention
  k_fattn<<<dim3(S_/128, B_*H_), dim3(256), 0, stream>>>(qkvb, vtb, attnb);

  // h += attn @ w_o^T + b_o
  k_gemm7<128,128,EPI_ADD32><<<dim3((M_/128)*(C_/128)), dim3(256), 0, stream>>>(
      attnb, C_, wob, C_, hbuf, C_, bo, C_/128, C_, nullptr);

  k_ln<false><<<dim3(M_), dim3(256), 0, stream>>>(nullptr, nullptr, hbuf, abuf, ln2w, ln2b);

  // fc = gelu(m @ w_fc^T + b_fc)
  k_gemm7<128,128,EPI_GELU><<<dim3((M_/128)*(DFF_/128)), dim3(256), 0, stream>>>(
      abuf, C_, wfcb, C_, fcb, DFF_, bfc, DFF_/128, C_, nullptr);

  // h += fc @ w_proj^T + b_proj
  k_gemm7<128,128,EPI_ADD32><<<dim3((M_/128)*(C_/128)), dim3(256), 0, stream>>>(
      fcb, DFF_, wprojb, DFF_, hbuf, C_, bproj, C_/128, DFF_, nullptr);

  // fused combine (replaces copy+scatter)
  k_combine<<<dim3(B_*T_), dim3(256), 0, stream>>>(x, map, wts, hbuf, out);
}